// Round 16
// baseline (561.729 us; speedup 1.0000x reference)
//
#include <hip/hip_runtime.h>
#include <cstdint>
#include <cstddef>

// ---------- types / helpers ----------
typedef float  v4f  __attribute__((ext_vector_type(4)));
typedef __bf16 v8bf __attribute__((ext_vector_type(8)));
typedef __bf16 v4bf __attribute__((ext_vector_type(4)));

__device__ __forceinline__ float b2f(unsigned short u) {
  union { unsigned int i; float f; } cv; cv.i = ((unsigned int)u) << 16; return cv.f;
}
__device__ __forceinline__ unsigned short f2b(float f) {
  union { float f; unsigned int i; } cv; cv.f = f;
  unsigned int i = cv.i;
  i += 0x7fffu + ((i >> 16) & 1u);      // round-to-nearest-even
  return (unsigned short)(i >> 16);
}
__device__ __forceinline__ unsigned short f2b_trunc(float f) {
  union { float f; unsigned int i; } cv; cv.f = f;
  return (unsigned short)(cv.i >> 16);  // truncate (cheap); P only
}
// tanh-form GELU: x*sigmoid(1.59577*(x+0.044715x^3)); |err vs erf-GELU| <= ~3e-4.
__device__ __forceinline__ float gelu_fast(float x) {
  const float u = x * (1.5957691216f + 0.07135481627f * x * x);
  return x * (1.0f / (1.0f + __expf(-u)));
}
__device__ __forceinline__ void g2l16(const unsigned short* g, unsigned short* l) {
  __builtin_amdgcn_global_load_lds(
      (const __attribute__((address_space(1))) void*)g,
      (__attribute__((address_space(3))) void*)l,
      16, 0, 0);
}

// ---------- transpose + fp32->bf16 convert: in[R,C] f32 -> out[C,R] bf16 ----------
__global__ __launch_bounds__(256) void transpose_k(const float* __restrict__ in,
                                                   unsigned short* __restrict__ out,
                                                   int R, int C) {
  __shared__ float tile[32][33];
  const int tx = threadIdx.x, ty = threadIdx.y;
  const int r0 = blockIdx.y * 32, c0 = blockIdx.x * 32;
#pragma unroll
  for (int j = 0; j < 4; ++j)
    tile[ty + 8 * j][tx] = in[(size_t)(r0 + ty + 8 * j) * C + c0 + tx];
  __syncthreads();
#pragma unroll
  for (int j = 0; j < 4; ++j)
    out[(size_t)(c0 + ty + 8 * j) * R + r0 + tx] = f2b(tile[tx][ty + 8 * j]);
}

// ---------- layernorm over DIM=1024 (fp32 or bf16 in, bf16 out) ----------
__global__ __launch_bounds__(256) void ln_kernel(const void* __restrict__ xp, int in_bf16,
                                                 const float* __restrict__ g,
                                                 const float* __restrict__ bta,
                                                 unsigned short* __restrict__ out) {
  const int r = blockIdx.x, t = threadIdx.x;
  float v0, v1, v2, v3;
  if (in_bf16) {
    const ushort4 raw = *(const ushort4*)((const unsigned short*)xp + (size_t)r * 1024 + t * 4);
    v0 = b2f(raw.x); v1 = b2f(raw.y); v2 = b2f(raw.z); v3 = b2f(raw.w);
  } else {
    const float4 raw = *(const float4*)((const float*)xp + (size_t)r * 1024 + t * 4);
    v0 = raw.x; v1 = raw.y; v2 = raw.z; v3 = raw.w;
  }
  float s  = v0 + v1 + v2 + v3;
  float s2 = v0 * v0 + v1 * v1 + v2 * v2 + v3 * v3;
#pragma unroll
  for (int off = 32; off > 0; off >>= 1) {
    s  += __shfl_down(s, off);
    s2 += __shfl_down(s2, off);
  }
  __shared__ float red[8];
  const int w = t >> 6, lane = t & 63;
  if (lane == 0) { red[w] = s; red[4 + w] = s2; }
  __syncthreads();
  if (t == 0) {
    float ts = red[0] + red[1] + red[2] + red[3];
    float t2 = red[4] + red[5] + red[6] + red[7];
    float mu = ts * (1.0f / 1024.0f);
    float var = t2 * (1.0f / 1024.0f) - mu * mu;
    red[0] = mu;
    red[1] = rsqrtf(var + 1e-5f);
  }
  __syncthreads();
  const float mu = red[0], rs = red[1];
  const float4 graw = *(const float4*)(g + t * 4);
  const float4 braw = *(const float4*)(bta + t * 4);
  ushort4 o;
  o.x = f2b((v0 - mu) * rs * graw.x + braw.x);
  o.y = f2b((v1 - mu) * rs * graw.y + braw.y);
  o.z = f2b((v2 - mu) * rs * graw.z + braw.z);
  o.w = f2b((v3 - mu) * rs * graw.w + braw.w);
  *(ushort4*)(out + (size_t)r * 1024 + t * 4) = o;
}

// ---------- MFMA GEMM: C[M,N] = A[M,K] @ Bt[N,K]^T (+bias)(+gelu)(+res) ----------
// r15 verified core: BK=64, 2-buf dist-1 prefetch, counted vmcnt(8), chunk-XOR
// swizzle both-sides, (256,2), swap_xy grids.
// THIS ROUND: coalesced epilogue via LDS. The old epilogue stored 2B/lane into
// 32B segments -> L2 write-allocate RMW (ffn1 FETCH 56MB vs 24 ideal; extra
// ~= C/2). Stage C-tile in the dead staging LDS, re-read with 8-lane x 16B =
// 128B full-line runs per instruction. bf16: 128x136 (34.8KB). fp32: 2 passes
// of 64x132 (33.8KB).
__global__ __launch_bounds__(256, 2) void gemm_bt(const unsigned short* __restrict__ A,
                                                  const unsigned short* __restrict__ Bt,
                                                  const float* __restrict__ bias,
                                                  const void* __restrict__ res, int res_bf16,
                                                  void* __restrict__ Cout,
                                                  int M, int N, int K, int act, int out_bf16,
                                                  int swap_xy) {
  __shared__ __align__(16) unsigned short shm[32768];   // 64KB: As[2]@0, Bs[2]@16384
  const int t = threadIdx.x;
  const int lane = t & 63, w = t >> 6;
  const int wr = (w >> 1) * 64, wc = (w & 1) * 64;
  const int lr = lane & 15, lq = lane >> 4;
  const int mb = swap_xy ? blockIdx.x : blockIdx.y;
  const int nb = swap_xy ? blockIdx.y : blockIdx.x;
  const int m0 = mb * 128, n0 = nb * 128;

  // staging: chunk c (0..1023) -> LDS linear (row=c>>3, chunk=c&7);
  // global source chunk = (c&7) ^ (row&7)  [both-sides swizzle]
  const unsigned short* Ag[4];
  const unsigned short* Bg[4];
#pragma unroll
  for (int j = 0; j < 4; ++j) {
    const int c = t + j * 256;
    const int row = c >> 3, ch = (c & 7) ^ (row & 7);
    Ag[j] = A  + (size_t)(m0 + row) * K + ch * 8;
    Bg[j] = Bt + (size_t)(n0 + row) * K + ch * 8;
  }

  v4f acc[4][4];
#pragma unroll
  for (int mi = 0; mi < 4; ++mi)
#pragma unroll
    for (int ni = 0; ni < 4; ++ni)
      acc[mi][ni] = (v4f){0.f, 0.f, 0.f, 0.f};

#define STAGE64(buf, ko)                                               \
  do {                                                                 \
    _Pragma("unroll")                                                  \
    for (int j = 0; j < 4; ++j) {                                      \
      g2l16(Ag[j] + (ko), shm + (buf) * 8192 + (t + j * 256) * 8);     \
      g2l16(Bg[j] + (ko), shm + 16384 + (buf) * 8192 + (t + j * 256) * 8); \
    }                                                                  \
  } while (0)

  const int nt = K >> 6;
  STAGE64(0, 0);

  for (int tt = 0; tt < nt; ++tt) {
    const int buf = tt & 1;
    if (tt + 1 < nt) {
      STAGE64(buf ^ 1, (tt + 1) << 6);
      // 8 just-issued loads (tile tt+1) stay in flight; tile tt guaranteed landed
      asm volatile("s_waitcnt vmcnt(8)" ::: "memory");
    } else {
      asm volatile("s_waitcnt vmcnt(0)" ::: "memory");
    }
    __builtin_amdgcn_s_barrier();
    asm volatile("" ::: "memory");

    const unsigned short* AsB = shm + buf * 8192;
    const unsigned short* BsB = shm + 16384 + buf * 8192;
#pragma unroll
    for (int kq = 0; kq < 2; ++kq) {
      const int ra = (((kq * 4 + lq) ^ (lr & 7)) << 3);   // swizzled read chunk
      v8bf af[4], bfr[4];
#pragma unroll
      for (int i = 0; i < 4; ++i) {
        af[i]  = *(const v8bf*)(AsB + (wr + i * 16 + lr) * 64 + ra);
        bfr[i] = *(const v8bf*)(BsB + (wc + i * 16 + lr) * 64 + ra);
      }
#pragma unroll
      for (int mi = 0; mi < 4; ++mi)
#pragma unroll
        for (int ni = 0; ni < 4; ++ni)
          acc[mi][ni] = __builtin_amdgcn_mfma_f32_16x16x32_bf16(af[mi], bfr[ni], acc[mi][ni], 0, 0, 0);
    }

    asm volatile("" ::: "memory");
    __builtin_amdgcn_s_barrier();
  }
#undef STAGE64

  // ---- coalesced epilogue (staging LDS is dead now) ----
  __syncthreads();   // full drain: every wave done with shm as staging
  if (out_bf16) {
    unsigned short* Cs = shm;                 // [128][136] bf16, 34.8KB
#pragma unroll
    for (int mi = 0; mi < 4; ++mi) {
#pragma unroll
      for (int ni = 0; ni < 4; ++ni) {
        const int col = wc + ni * 16 + lr;
        const float bv = bias ? bias[n0 + col] : 0.0f;
#pragma unroll
        for (int r = 0; r < 4; ++r) {
          const int row = wr + mi * 16 + lq * 4 + r;
          float v = acc[mi][ni][r] + bv;
          if (act) v = gelu_fast(v);
          if (res) {
            v += res_bf16 ? b2f(((const unsigned short*)res)[(size_t)(m0 + row) * N + n0 + col])
                          : ((const float*)res)[(size_t)(m0 + row) * N + n0 + col];
          }
          Cs[row * 136 + col] = f2b(v);
        }
      }
    }
    __syncthreads();
    const int rr = t >> 3, ch = t & 7;
#pragma unroll
    for (int rb = 0; rb < 4; ++rb) {
      const int row = rb * 32 + rr;
#pragma unroll
      for (int j = 0; j < 2; ++j) {
        const int col = j * 64 + ch * 8;
        const uint4 val = *(const uint4*)(Cs + row * 136 + col);
        *(uint4*)((unsigned short*)Cout + (size_t)(m0 + row) * N + n0 + col) = val;
      }
    }
  } else {
    float* Cs = (float*)shm;                  // [64][132] f32 per pass, 33.8KB
#pragma unroll
    for (int pass = 0; pass < 2; ++pass) {
      if ((wr >> 6) == pass) {
#pragma unroll
        for (int mi = 0; mi < 4; ++mi) {
#pragma unroll
          for (int ni = 0; ni < 4; ++ni) {
            const int col = wc + ni * 16 + lr;
            const float bv = bias ? bias[n0 + col] : 0.0f;
#pragma unroll
            for (int r = 0; r < 4; ++r) {
              const int row = wr + mi * 16 + lq * 4 + r;
              float v = acc[mi][ni][r] + bv;
              if (act) v = gelu_fast(v);
              if (res) {
                v += res_bf16 ? b2f(((const unsigned short*)res)[(size_t)(m0 + row) * N + n0 + col])
                              : ((const float*)res)[(size_t)(m0 + row) * N + n0 + col];
              }
              Cs[(row & 63) * 132 + col] = v;
            }
          }
        }
      }
      __syncthreads();
      const int rr = t >> 3, ch = t & 7;
#pragma unroll
      for (int rb = 0; rb < 2; ++rb) {
        const int row = pass * 64 + rb * 32 + rr;
        const int lrow = rb * 32 + rr;
#pragma unroll
        for (int j = 0; j < 4; ++j) {
          const int col = j * 32 + ch * 4;
          const float4 val = *(const float4*)(Cs + lrow * 132 + col);
          *(float4*)((float*)Cout + (size_t)(m0 + row) * N + n0 + col) = val;
        }
      }
      __syncthreads();
    }
  }
}

// ---------- V restage: qkv[token][3072] v-part -> Vt[(b*16+h)*64+d][2048 tokens] ----------
__global__ __launch_bounds__(256) void vt_k(const unsigned short* __restrict__ qkv,
                                            unsigned short* __restrict__ Vt) {
  const int t = threadIdx.x;
  const int n = blockIdx.x * 256 + t, h = blockIdx.y, b = blockIdx.z;
  const size_t src = (size_t)(b * 2048 + n) * 3072 + 2048 + h * 64;
  unsigned short v[64];
#pragma unroll
  for (int j = 0; j < 8; ++j)
    *(uint4*)(v + j * 8) = *(const uint4*)(qkv + src + j * 8);
  const size_t dstbase = ((size_t)(b * 16 + h) * 64) * 2048 + n;
#pragma unroll
  for (int d = 0; d < 64; ++d)
    Vt[dstbase + (size_t)d * 2048] = v[d];
}

// ---------- MFMA flash attention (r14 verified, <=113 us) ----------
// Swapped QK^T (mfma(K,Q)): lane holds P[q=lr][k=ni*16+lq*4+r] -> b64 Ps
// stores; lane-local lsum; (256,3); Q pre-scaled 1/8; __expf softmax.
__global__ __launch_bounds__(256, 3) void attn_mfma(const unsigned short* __restrict__ qkv,
                                                    const unsigned short* __restrict__ Vt,
                                                    unsigned short* __restrict__ out) {
  __shared__ __align__(16) unsigned short Ks[64 * 80];
  __shared__ __align__(16) unsigned short Vs[64 * 80];
  __shared__ __align__(16) unsigned short Ps[4][32 * 76];
  const int t = threadIdx.x;
  const int lane = t & 63, w = t >> 6;
  const int lr = lane & 15, lq = lane >> 4;
  const int h = blockIdx.x, b = blockIdx.z;
  const int q0 = blockIdx.y * 128 + w * 32;

  v8bf aq[2][2];
#pragma unroll
  for (int mi = 0; mi < 2; ++mi)
#pragma unroll
    for (int kq = 0; kq < 2; ++kq) {
      aq[mi][kq] = *(const v8bf*)(qkv + (size_t)(b * 2048 + q0 + mi * 16 + lr) * 3072
                                  + h * 64 + kq * 32 + lq * 8);
#pragma unroll
      for (int j = 0; j < 8; ++j)
        aq[mi][kq][j] = (__bf16)((float)aq[mi][kq][j] * 0.125f);  // exact: 2^-3
    }

  v4f acc_o[2][4];
  float lsum[2];
#pragma unroll
  for (int mi = 0; mi < 2; ++mi)
#pragma unroll
    for (int di = 0; di < 4; ++di)
      acc_o[mi][di] = (v4f){0.f, 0.f, 0.f, 0.f};
  lsum[0] = 0.0f; lsum[1] = 0.0f;

  // per-thread K/V staging addresses (2 chunks of 16B each)
  const int sc0 = t, sc1 = t + 256;
  const int kr0 = sc0 >> 3, ko0 = (sc0 & 7) * 8;
  const int kr1 = sc1 >> 3, ko1 = (sc1 & 7) * 8;
  const unsigned short* Kg0 = qkv + (size_t)(b * 2048 + kr0) * 3072 + 1024 + h * 64 + ko0;
  const unsigned short* Kg1 = qkv + (size_t)(b * 2048 + kr1) * 3072 + 1024 + h * 64 + ko1;
  const unsigned short* Vg0 = Vt + ((size_t)(b * 16 + h) * 64 + kr0) * 2048 + ko0;
  const unsigned short* Vg1 = Vt + ((size_t)(b * 16 + h) * 64 + kr1) * 2048 + ko1;

  // prologue: tile 0 into LDS
  uint4 kreg0 = *(const uint4*)(Kg0);
  uint4 kreg1 = *(const uint4*)(Kg1);
  uint4 vreg0 = *(const uint4*)(Vg0);
  uint4 vreg1 = *(const uint4*)(Vg1);
  *(uint4*)(Ks + kr0 * 80 + ko0) = kreg0;
  *(uint4*)(Ks + kr1 * 80 + ko1) = kreg1;
  *(uint4*)(Vs + kr0 * 80 + ko0) = vreg0;
  *(uint4*)(Vs + kr1 * 80 + ko1) = vreg1;
  __syncthreads();

  for (int kt = 0; kt < 32; ++kt) {
    // issue next tile's global loads early; latency hides under compute
    if (kt < 31) {
      const size_t kn = (size_t)(kt + 1) * 64;
      kreg0 = *(const uint4*)(Kg0 + kn * 3072);
      kreg1 = *(const uint4*)(Kg1 + kn * 3072);
      vreg0 = *(const uint4*)(Vg0 + kn);
      vreg1 = *(const uint4*)(Vg1 + kn);
    }

    // ---- QK^T, SWAPPED operands: D[k-row][q-col] ----
    v4f s_acc[2][4];
#pragma unroll
    for (int mi = 0; mi < 2; ++mi)
#pragma unroll
      for (int ni = 0; ni < 4; ++ni)
        s_acc[mi][ni] = (v4f){0.f, 0.f, 0.f, 0.f};
#pragma unroll
    for (int kq = 0; kq < 2; ++kq) {
      v8bf bk[4];
#pragma unroll
      for (int ni = 0; ni < 4; ++ni)
        bk[ni] = *(const v8bf*)(Ks + (ni * 16 + lr) * 80 + kq * 32 + lq * 8);
      __builtin_amdgcn_s_setprio(1);
#pragma unroll
      for (int mi = 0; mi < 2; ++mi)
#pragma unroll
        for (int ni = 0; ni < 4; ++ni)
          s_acc[mi][ni] = __builtin_amdgcn_mfma_f32_16x16x32_bf16(bk[ni], aq[mi][kq], s_acc[mi][ni], 0, 0, 0);
      __builtin_amdgcn_s_setprio(0);
    }

    // ---- softmax: lane holds P[q=lr][k=ni*16+lq*4+r] -> vectorized b64 store ----
#pragma unroll
    for (int mi = 0; mi < 2; ++mi)
#pragma unroll
      for (int ni = 0; ni < 4; ++ni) {
        const unsigned short p0 = f2b_trunc(__expf(s_acc[mi][ni][0]));
        const unsigned short p1 = f2b_trunc(__expf(s_acc[mi][ni][1]));
        const unsigned short p2 = f2b_trunc(__expf(s_acc[mi][ni][2]));
        const unsigned short p3 = f2b_trunc(__expf(s_acc[mi][ni][3]));
        lsum[mi] += (b2f(p0) + b2f(p1)) + (b2f(p2) + b2f(p3));
        ushort4 pk; pk.x = p0; pk.y = p1; pk.z = p2; pk.w = p3;
        *(ushort4*)(Ps[w] + (mi * 16 + lr) * 76 + ni * 16 + lq * 4) = pk;
      }

    // ---- P @ V (reads unchanged: P[q][k] row-major, stride 76) ----
#pragma unroll
    for (int ks = 0; ks < 2; ++ks) {
      v8bf ap[2], bv[4];
#pragma unroll
      for (int mi = 0; mi < 2; ++mi) {
        const unsigned short* base = Ps[w] + (mi * 16 + lr) * 76 + ks * 32 + lq * 8;
        const v4bf lo = *(const v4bf*)(base);
        const v4bf hi = *(const v4bf*)(base + 4);
        ap[mi] = __builtin_shufflevector(lo, hi, 0, 1, 2, 3, 4, 5, 6, 7);
      }
#pragma unroll
      for (int di = 0; di < 4; ++di)
        bv[di] = *(const v8bf*)(Vs + (di * 16 + lr) * 80 + ks * 32 + lq * 8);
      __builtin_amdgcn_s_setprio(1);
#pragma unroll
      for (int mi = 0; mi < 2; ++mi)
#pragma unroll
        for (int di = 0; di < 4; ++di)
          acc_o[mi][di] = __builtin_amdgcn_mfma_f32_16x16x32_bf16(ap[mi], bv[di], acc_o[mi][di], 0, 0, 0);
      __builtin_amdgcn_s_setprio(0);
    }

    __syncthreads();            // all waves done reading Ks/Vs
    if (kt < 31) {
      *(uint4*)(Ks + kr0 * 80 + ko0) = kreg0;
      *(uint4*)(Ks + kr1 * 80 + ko1) = kreg1;
      *(uint4*)(Vs + kr0 * 80 + ko0) = vreg0;
      *(uint4*)(Vs + kr1 * 80 + ko1) = vreg1;
    }
    __syncthreads();            // next tile visible
  }

  // lsum[mi] holds partial sum over k for q = mi*16 + lr, spread across lq group.
  float linv[2];
#pragma unroll
  for (int mi = 0; mi < 2; ++mi) {
    float v = lsum[mi];
    v += __shfl_xor(v, 16);
    v += __shfl_xor(v, 32);
    linv[mi] = 1.0f / v;
  }
  // redistribute: epilogue lane needs 1/sum for q = mi*16 + lq*4 + r,
  // held by lane (lq*4+r) (all lanes in its lq-group have the total).
  float inv[2][4];
#pragma unroll
  for (int mi = 0; mi < 2; ++mi)
#pragma unroll
    for (int r = 0; r < 4; ++r)
      inv[mi][r] = __shfl(linv[mi], lq * 4 + r);

#pragma unroll
  for (int mi = 0; mi < 2; ++mi)
#pragma unroll
    for (int di = 0; di < 4; ++di)
#pragma unroll
      for (int r = 0; r < 4; ++r)
        out[(size_t)(b * 2048 + q0 + mi * 16 + lq * 4 + r) * 1024 + h * 64 + di * 16 + lr] =
            f2b(acc_o[mi][di][r] * inv[mi][r]);
}

// ---------- launch ----------
// ws layout (112 MiB): T_a [0,8M) wt_qkv->wt_w1; T_b [8,16M) wt_proj->wt_w2;
// x2 bf16 [16,32M); Vt [32,48M); H [48,64M) h->o; qkv [64,112M);
// h3 [48,112M) overlays dead H+qkv; h2 bf16 in d_out scratch.
extern "C" void kernel_launch(void* const* d_in, const int* in_sizes, int n_in,
                              void* d_out, int out_size, void* d_ws, size_t ws_size,
                              hipStream_t stream) {
  (void)in_sizes; (void)n_in; (void)out_size; (void)ws_size;
  const float* x      = (const float*)d_in[0];
  const float* w_qkv  = (const float*)d_in[1];
  const float* w_proj = (const float*)d_in[2];
  const float* b_proj = (const float*)d_in[3];
  const float* ln1_g  = (const float*)d_in[4];
  const float* ln1_b  = (const float*)d_in[5];
  const float* w1     = (const float*)d_in[6];
  const float* b1     = (const float*)d_in[7];
  const float* w2     = (const float*)d_in[8];
  const float* b2     = (const float*)d_in[9];
  const float* ln2_g  = (const float*)d_in[10];
  const float* ln2_b  = (const float*)d_in[11];
  float* out = (float*)d_out;

  char* ws = (char*)d_ws;
  unsigned short* T_a   = (unsigned short*)(ws);
  unsigned short* T_b   = (unsigned short*)(ws + 8388608);
  unsigned short* x2buf = (unsigned short*)(ws + 16777216);   // bf16 [8192,1024]
  unsigned short* Vtbuf = (unsigned short*)(ws + 33554432);
  unsigned short* Hbuf  = (unsigned short*)(ws + 50331648);
  unsigned short* qkvb  = (unsigned short*)(ws + 67108864);
  unsigned short* h3buf = (unsigned short*)(ws + 50331648);
  unsigned short* h2buf = (unsigned short*)d_out;

  const dim3 tb(32, 8);
  transpose_k<<<dim3(96, 32),  tb, 0, stream>>>(w_qkv,  T_a, 1024, 3072);
  transpose_k<<<dim3(32, 32),  tb, 0, stream>>>(w_proj, T_b, 1024, 1024);
  // h = LN1(x)
  ln_kernel<<<8192, 256, 0, stream>>>(x, 0, ln1_g, ln1_b, Hbuf);
  // qkv = h @ w_qkv  (swap_xy=1)
  gemm_bt<<<dim3(64, 24), 256, 0, stream>>>(Hbuf, T_a, nullptr, nullptr, 0, qkvb, 8192, 3072, 1024, 0, 1, 1);
  transpose_k<<<dim3(128, 32), tb, 0, stream>>>(w1, T_a, 1024, 4096);
  // attention
  vt_k<<<dim3(8, 16, 4), 256, 0, stream>>>(qkvb, Vtbuf);
  attn_mfma<<<dim3(16, 16, 4), 256, 0, stream>>>(qkvb, Vtbuf, Hbuf);
  // x2 = o @ w_proj + b_proj + x  (bf16 out, swizzle)
  gemm_bt<<<dim3(64, 8), 256, 0, stream>>>(Hbuf, T_b, b_proj, x, 0, x2buf, 8192, 1024, 1024, 0, 1, 1);
  transpose_k<<<dim3(32, 128), tb, 0, stream>>>(w2, T_b, 4096, 1024);
  // h2 = LN2(x2)
  ln_kernel<<<8192, 256, 0, stream>>>(x2buf, 1, ln2_g, ln2_b, h2buf);
  // h3 = gelu(h2 @ w1 + b1)  (swap_xy=1)
  gemm_bt<<<dim3(64, 32), 256, 0, stream>>>(h2buf, T_a, b1, nullptr, 0, h3buf, 8192, 4096, 1024, 1, 1, 1);
  // out = h3 @ w2 + b2 + x2  (fp32 out, swizzle)
  gemm_bt<<<dim3(64, 8), 256, 0, stream>>>(h3buf, T_b, b2, x2buf, 1, out, 8192, 1024, 4096, 0, 0, 1);
}

// Round 17
// 546.240 us; speedup vs baseline: 1.0284x; 1.0284x over previous
//
#include <hip/hip_runtime.h>
#include <cstdint>
#include <cstddef>

// ---------- types / helpers ----------
typedef float  v4f  __attribute__((ext_vector_type(4)));
typedef __bf16 v8bf __attribute__((ext_vector_type(8)));
typedef __bf16 v4bf __attribute__((ext_vector_type(4)));

__device__ __forceinline__ float b2f(unsigned short u) {
  union { unsigned int i; float f; } cv; cv.i = ((unsigned int)u) << 16; return cv.f;
}
__device__ __forceinline__ unsigned short f2b(float f) {
  union { float f; unsigned int i; } cv; cv.f = f;
  unsigned int i = cv.i;
  i += 0x7fffu + ((i >> 16) & 1u);      // round-to-nearest-even
  return (unsigned short)(i >> 16);
}
__device__ __forceinline__ unsigned short f2b_trunc(float f) {
  union { float f; unsigned int i; } cv; cv.f = f;
  return (unsigned short)(cv.i >> 16);  // truncate (cheap); P only
}
// tanh-form GELU: x*sigmoid(1.59577*(x+0.044715x^3)); |err vs erf-GELU| <= ~3e-4.
__device__ __forceinline__ float gelu_fast(float x) {
  const float u = x * (1.5957691216f + 0.07135481627f * x * x);
  return x * (1.0f / (1.0f + __expf(-u)));
}
__device__ __forceinline__ void g2l16(const unsigned short* g, unsigned short* l) {
  __builtin_amdgcn_global_load_lds(
      (const __attribute__((address_space(1))) void*)g,
      (__attribute__((address_space(3))) void*)l,
      16, 0, 0);
}

// ---------- transpose + fp32->bf16 convert: in[R,C] f32 -> out[C,R] bf16 ----------
__global__ __launch_bounds__(256) void transpose_k(const float* __restrict__ in,
                                                   unsigned short* __restrict__ out,
                                                   int R, int C) {
  __shared__ float tile[32][33];
  const int tx = threadIdx.x, ty = threadIdx.y;
  const int r0 = blockIdx.y * 32, c0 = blockIdx.x * 32;
#pragma unroll
  for (int j = 0; j < 4; ++j)
    tile[ty + 8 * j][tx] = in[(size_t)(r0 + ty + 8 * j) * C + c0 + tx];
  __syncthreads();
#pragma unroll
  for (int j = 0; j < 4; ++j)
    out[(size_t)(c0 + ty + 8 * j) * R + r0 + tx] = f2b(tile[tx][ty + 8 * j]);
}

// ---------- layernorm over DIM=1024 (fp32 or bf16 in, bf16 out) ----------
__global__ __launch_bounds__(256) void ln_kernel(const void* __restrict__ xp, int in_bf16,
                                                 const float* __restrict__ g,
                                                 const float* __restrict__ bta,
                                                 unsigned short* __restrict__ out) {
  const int r = blockIdx.x, t = threadIdx.x;
  float v0, v1, v2, v3;
  if (in_bf16) {
    const ushort4 raw = *(const ushort4*)((const unsigned short*)xp + (size_t)r * 1024 + t * 4);
    v0 = b2f(raw.x); v1 = b2f(raw.y); v2 = b2f(raw.z); v3 = b2f(raw.w);
  } else {
    const float4 raw = *(const float4*)((const float*)xp + (size_t)r * 1024 + t * 4);
    v0 = raw.x; v1 = raw.y; v2 = raw.z; v3 = raw.w;
  }
  float s  = v0 + v1 + v2 + v3;
  float s2 = v0 * v0 + v1 * v1 + v2 * v2 + v3 * v3;
#pragma unroll
  for (int off = 32; off > 0; off >>= 1) {
    s  += __shfl_down(s, off);
    s2 += __shfl_down(s2, off);
  }
  __shared__ float red[8];
  const int w = t >> 6, lane = t & 63;
  if (lane == 0) { red[w] = s; red[4 + w] = s2; }
  __syncthreads();
  if (t == 0) {
    float ts = red[0] + red[1] + red[2] + red[3];
    float t2 = red[4] + red[5] + red[6] + red[7];
    float mu = ts * (1.0f / 1024.0f);
    float var = t2 * (1.0f / 1024.0f) - mu * mu;
    red[0] = mu;
    red[1] = rsqrtf(var + 1e-5f);
  }
  __syncthreads();
  const float mu = red[0], rs = red[1];
  const float4 graw = *(const float4*)(g + t * 4);
  const float4 braw = *(const float4*)(bta + t * 4);
  ushort4 o;
  o.x = f2b((v0 - mu) * rs * graw.x + braw.x);
  o.y = f2b((v1 - mu) * rs * graw.y + braw.y);
  o.z = f2b((v2 - mu) * rs * graw.z + braw.z);
  o.w = f2b((v3 - mu) * rs * graw.w + braw.w);
  *(ushort4*)(out + (size_t)r * 1024 + t * 4) = o;
}

// ---------- MFMA GEMM: C[M,N] = A[M,K] @ Bt[N,K]^T (+bias)(+gelu)(+res) ----------
// r15 verified core: BK=64, 2-buf dist-1 prefetch, counted vmcnt(8), chunk-XOR
// swizzle both-sides, (256,2), swap_xy grids.
// Epilogue split (r16 post-mortem): bf16 out -> LDS-staged coalesced stores
// (measured: ffn1 115.9->105.1); fp32 out -> DIRECT stores (r16's 2-pass staged
// fp32 epilogue cost ~16us in extra barriers/idle waves; fp32 4B/lane = 64B
// segments, tolerable).
__global__ __launch_bounds__(256, 2) void gemm_bt(const unsigned short* __restrict__ A,
                                                  const unsigned short* __restrict__ Bt,
                                                  const float* __restrict__ bias,
                                                  const void* __restrict__ res, int res_bf16,
                                                  void* __restrict__ Cout,
                                                  int M, int N, int K, int act, int out_bf16,
                                                  int swap_xy) {
  __shared__ __align__(16) unsigned short shm[32768];   // 64KB: As[2]@0, Bs[2]@16384
  const int t = threadIdx.x;
  const int lane = t & 63, w = t >> 6;
  const int wr = (w >> 1) * 64, wc = (w & 1) * 64;
  const int lr = lane & 15, lq = lane >> 4;
  const int mb = swap_xy ? blockIdx.x : blockIdx.y;
  const int nb = swap_xy ? blockIdx.y : blockIdx.x;
  const int m0 = mb * 128, n0 = nb * 128;

  // staging: chunk c (0..1023) -> LDS linear (row=c>>3, chunk=c&7);
  // global source chunk = (c&7) ^ (row&7)  [both-sides swizzle]
  const unsigned short* Ag[4];
  const unsigned short* Bg[4];
#pragma unroll
  for (int j = 0; j < 4; ++j) {
    const int c = t + j * 256;
    const int row = c >> 3, ch = (c & 7) ^ (row & 7);
    Ag[j] = A  + (size_t)(m0 + row) * K + ch * 8;
    Bg[j] = Bt + (size_t)(n0 + row) * K + ch * 8;
  }

  v4f acc[4][4];
#pragma unroll
  for (int mi = 0; mi < 4; ++mi)
#pragma unroll
    for (int ni = 0; ni < 4; ++ni)
      acc[mi][ni] = (v4f){0.f, 0.f, 0.f, 0.f};

#define STAGE64(buf, ko)                                               \
  do {                                                                 \
    _Pragma("unroll")                                                  \
    for (int j = 0; j < 4; ++j) {                                      \
      g2l16(Ag[j] + (ko), shm + (buf) * 8192 + (t + j * 256) * 8);     \
      g2l16(Bg[j] + (ko), shm + 16384 + (buf) * 8192 + (t + j * 256) * 8); \
    }                                                                  \
  } while (0)

  const int nt = K >> 6;
  STAGE64(0, 0);

  for (int tt = 0; tt < nt; ++tt) {
    const int buf = tt & 1;
    if (tt + 1 < nt) {
      STAGE64(buf ^ 1, (tt + 1) << 6);
      // 8 just-issued loads (tile tt+1) stay in flight; tile tt guaranteed landed
      asm volatile("s_waitcnt vmcnt(8)" ::: "memory");
    } else {
      asm volatile("s_waitcnt vmcnt(0)" ::: "memory");
    }
    __builtin_amdgcn_s_barrier();
    asm volatile("" ::: "memory");

    const unsigned short* AsB = shm + buf * 8192;
    const unsigned short* BsB = shm + 16384 + buf * 8192;
#pragma unroll
    for (int kq = 0; kq < 2; ++kq) {
      const int ra = (((kq * 4 + lq) ^ (lr & 7)) << 3);   // swizzled read chunk
      v8bf af[4], bfr[4];
#pragma unroll
      for (int i = 0; i < 4; ++i) {
        af[i]  = *(const v8bf*)(AsB + (wr + i * 16 + lr) * 64 + ra);
        bfr[i] = *(const v8bf*)(BsB + (wc + i * 16 + lr) * 64 + ra);
      }
#pragma unroll
      for (int mi = 0; mi < 4; ++mi)
#pragma unroll
        for (int ni = 0; ni < 4; ++ni)
          acc[mi][ni] = __builtin_amdgcn_mfma_f32_16x16x32_bf16(af[mi], bfr[ni], acc[mi][ni], 0, 0, 0);
    }

    asm volatile("" ::: "memory");
    __builtin_amdgcn_s_barrier();
  }
#undef STAGE64

  if (out_bf16) {
    // ---- coalesced bf16 epilogue via dead staging LDS (measured -9% on ffn1) ----
    __syncthreads();
    unsigned short* Cs = shm;                 // [128][136] bf16, 34.8KB
#pragma unroll
    for (int mi = 0; mi < 4; ++mi) {
#pragma unroll
      for (int ni = 0; ni < 4; ++ni) {
        const int col = wc + ni * 16 + lr;
        const float bv = bias ? bias[n0 + col] : 0.0f;
#pragma unroll
        for (int r = 0; r < 4; ++r) {
          const int row = wr + mi * 16 + lq * 4 + r;
          float v = acc[mi][ni][r] + bv;
          if (act) v = gelu_fast(v);
          if (res) {
            v += res_bf16 ? b2f(((const unsigned short*)res)[(size_t)(m0 + row) * N + n0 + col])
                          : ((const float*)res)[(size_t)(m0 + row) * N + n0 + col];
          }
          Cs[row * 136 + col] = f2b(v);
        }
      }
    }
    __syncthreads();
    const int rr = t >> 3, ch = t & 7;
#pragma unroll
    for (int rb = 0; rb < 4; ++rb) {
      const int row = rb * 32 + rr;
#pragma unroll
      for (int j = 0; j < 2; ++j) {
        const int col = j * 64 + ch * 8;
        const uint4 val = *(const uint4*)(Cs + row * 136 + col);
        *(uint4*)((unsigned short*)Cout + (size_t)(m0 + row) * N + n0 + col) = val;
      }
    }
  } else {
    // ---- direct fp32 epilogue (r15-verified; staged version regressed) ----
#pragma unroll
    for (int mi = 0; mi < 4; ++mi) {
#pragma unroll
      for (int ni = 0; ni < 4; ++ni) {
        const int col = n0 + wc + ni * 16 + lr;
        const float bv = bias ? bias[col] : 0.0f;
#pragma unroll
        for (int r = 0; r < 4; ++r) {
          const int row = m0 + wr + mi * 16 + lq * 4 + r;
          float v = acc[mi][ni][r] + bv;
          if (act) v = gelu_fast(v);
          if (res) {
            v += res_bf16 ? b2f(((const unsigned short*)res)[(size_t)row * N + col])
                          : ((const float*)res)[(size_t)row * N + col];
          }
          ((float*)Cout)[(size_t)row * N + col] = v;
        }
      }
    }
  }
}

// ---------- V restage: qkv[token][3072] v-part -> Vt[(b*16+h)*64+d][2048 tokens] ----------
__global__ __launch_bounds__(256) void vt_k(const unsigned short* __restrict__ qkv,
                                            unsigned short* __restrict__ Vt) {
  const int t = threadIdx.x;
  const int n = blockIdx.x * 256 + t, h = blockIdx.y, b = blockIdx.z;
  const size_t src = (size_t)(b * 2048 + n) * 3072 + 2048 + h * 64;
  unsigned short v[64];
#pragma unroll
  for (int j = 0; j < 8; ++j)
    *(uint4*)(v + j * 8) = *(const uint4*)(qkv + src + j * 8);
  const size_t dstbase = ((size_t)(b * 16 + h) * 64) * 2048 + n;
#pragma unroll
  for (int d = 0; d < 64; ++d)
    Vt[dstbase + (size_t)d * 2048] = v[d];
}

// ---------- MFMA flash attention (r14/r16 verified, 105.1 us) ----------
// Swapped QK^T (mfma(K,Q)): lane holds P[q=lr][k=ni*16+lq*4+r] -> b64 Ps
// stores; lane-local lsum; (256,3); Q pre-scaled 1/8; __expf softmax.
__global__ __launch_bounds__(256, 3) void attn_mfma(const unsigned short* __restrict__ qkv,
                                                    const unsigned short* __restrict__ Vt,
                                                    unsigned short* __restrict__ out) {
  __shared__ __align__(16) unsigned short Ks[64 * 80];
  __shared__ __align__(16) unsigned short Vs[64 * 80];
  __shared__ __align__(16) unsigned short Ps[4][32 * 76];
  const int t = threadIdx.x;
  const int lane = t & 63, w = t >> 6;
  const int lr = lane & 15, lq = lane >> 4;
  const int h = blockIdx.x, b = blockIdx.z;
  const int q0 = blockIdx.y * 128 + w * 32;

  v8bf aq[2][2];
#pragma unroll
  for (int mi = 0; mi < 2; ++mi)
#pragma unroll
    for (int kq = 0; kq < 2; ++kq) {
      aq[mi][kq] = *(const v8bf*)(qkv + (size_t)(b * 2048 + q0 + mi * 16 + lr) * 3072
                                  + h * 64 + kq * 32 + lq * 8);
#pragma unroll
      for (int j = 0; j < 8; ++j)
        aq[mi][kq][j] = (__bf16)((float)aq[mi][kq][j] * 0.125f);  // exact: 2^-3
    }

  v4f acc_o[2][4];
  float lsum[2];
#pragma unroll
  for (int mi = 0; mi < 2; ++mi)
#pragma unroll
    for (int di = 0; di < 4; ++di)
      acc_o[mi][di] = (v4f){0.f, 0.f, 0.f, 0.f};
  lsum[0] = 0.0f; lsum[1] = 0.0f;

  // per-thread K/V staging addresses (2 chunks of 16B each)
  const int sc0 = t, sc1 = t + 256;
  const int kr0 = sc0 >> 3, ko0 = (sc0 & 7) * 8;
  const int kr1 = sc1 >> 3, ko1 = (sc1 & 7) * 8;
  const unsigned short* Kg0 = qkv + (size_t)(b * 2048 + kr0) * 3072 + 1024 + h * 64 + ko0;
  const unsigned short* Kg1 = qkv + (size_t)(b * 2048 + kr1) * 3072 + 1024 + h * 64 + ko1;
  const unsigned short* Vg0 = Vt + ((size_t)(b * 16 + h) * 64 + kr0) * 2048 + ko0;
  const unsigned short* Vg1 = Vt + ((size_t)(b * 16 + h) * 64 + kr1) * 2048 + ko1;

  // prologue: tile 0 into LDS
  uint4 kreg0 = *(const uint4*)(Kg0);
  uint4 kreg1 = *(const uint4*)(Kg1);
  uint4 vreg0 = *(const uint4*)(Vg0);
  uint4 vreg1 = *(const uint4*)(Vg1);
  *(uint4*)(Ks + kr0 * 80 + ko0) = kreg0;
  *(uint4*)(Ks + kr1 * 80 + ko1) = kreg1;
  *(uint4*)(Vs + kr0 * 80 + ko0) = vreg0;
  *(uint4*)(Vs + kr1 * 80 + ko1) = vreg1;
  __syncthreads();

  for (int kt = 0; kt < 32; ++kt) {
    // issue next tile's global loads early; latency hides under compute
    if (kt < 31) {
      const size_t kn = (size_t)(kt + 1) * 64;
      kreg0 = *(const uint4*)(Kg0 + kn * 3072);
      kreg1 = *(const uint4*)(Kg1 + kn * 3072);
      vreg0 = *(const uint4*)(Vg0 + kn);
      vreg1 = *(const uint4*)(Vg1 + kn);
    }

    // ---- QK^T, SWAPPED operands: D[k-row][q-col] ----
    v4f s_acc[2][4];
#pragma unroll
    for (int mi = 0; mi < 2; ++mi)
#pragma unroll
      for (int ni = 0; ni < 4; ++ni)
        s_acc[mi][ni] = (v4f){0.f, 0.f, 0.f, 0.f};
#pragma unroll
    for (int kq = 0; kq < 2; ++kq) {
      v8bf bk[4];
#pragma unroll
      for (int ni = 0; ni < 4; ++ni)
        bk[ni] = *(const v8bf*)(Ks + (ni * 16 + lr) * 80 + kq * 32 + lq * 8);
      __builtin_amdgcn_s_setprio(1);
#pragma unroll
      for (int mi = 0; mi < 2; ++mi)
#pragma unroll
        for (int ni = 0; ni < 4; ++ni)
          s_acc[mi][ni] = __builtin_amdgcn_mfma_f32_16x16x32_bf16(bk[ni], aq[mi][kq], s_acc[mi][ni], 0, 0, 0);
      __builtin_amdgcn_s_setprio(0);
    }

    // ---- softmax: lane holds P[q=lr][k=ni*16+lq*4+r] -> vectorized b64 store ----
#pragma unroll
    for (int mi = 0; mi < 2; ++mi)
#pragma unroll
      for (int ni = 0; ni < 4; ++ni) {
        const unsigned short p0 = f2b_trunc(__expf(s_acc[mi][ni][0]));
        const unsigned short p1 = f2b_trunc(__expf(s_acc[mi][ni][1]));
        const unsigned short p2 = f2b_trunc(__expf(s_acc[mi][ni][2]));
        const unsigned short p3 = f2b_trunc(__expf(s_acc[mi][ni][3]));
        lsum[mi] += (b2f(p0) + b2f(p1)) + (b2f(p2) + b2f(p3));
        ushort4 pk; pk.x = p0; pk.y = p1; pk.z = p2; pk.w = p3;
        *(ushort4*)(Ps[w] + (mi * 16 + lr) * 76 + ni * 16 + lq * 4) = pk;
      }

    // ---- P @ V (reads unchanged: P[q][k] row-major, stride 76) ----
#pragma unroll
    for (int ks = 0; ks < 2; ++ks) {
      v8bf ap[2], bv[4];
#pragma unroll
      for (int mi = 0; mi < 2; ++mi) {
        const unsigned short* base = Ps[w] + (mi * 16 + lr) * 76 + ks * 32 + lq * 8;
        const v4bf lo = *(const v4bf*)(base);
        const v4bf hi = *(const v4bf*)(base + 4);
        ap[mi] = __builtin_shufflevector(lo, hi, 0, 1, 2, 3, 4, 5, 6, 7);
      }
#pragma unroll
      for (int di = 0; di < 4; ++di)
        bv[di] = *(const v8bf*)(Vs + (di * 16 + lr) * 80 + ks * 32 + lq * 8);
      __builtin_amdgcn_s_setprio(1);
#pragma unroll
      for (int mi = 0; mi < 2; ++mi)
#pragma unroll
        for (int di = 0; di < 4; ++di)
          acc_o[mi][di] = __builtin_amdgcn_mfma_f32_16x16x32_bf16(ap[mi], bv[di], acc_o[mi][di], 0, 0, 0);
      __builtin_amdgcn_s_setprio(0);
    }

    __syncthreads();            // all waves done reading Ks/Vs
    if (kt < 31) {
      *(uint4*)(Ks + kr0 * 80 + ko0) = kreg0;
      *(uint4*)(Ks + kr1 * 80 + ko1) = kreg1;
      *(uint4*)(Vs + kr0 * 80 + ko0) = vreg0;
      *(uint4*)(Vs + kr1 * 80 + ko1) = vreg1;
    }
    __syncthreads();            // next tile visible
  }

  // lsum[mi] holds partial sum over k for q = mi*16 + lr, spread across lq group.
  float linv[2];
#pragma unroll
  for (int mi = 0; mi < 2; ++mi) {
    float v = lsum[mi];
    v += __shfl_xor(v, 16);
    v += __shfl_xor(v, 32);
    linv[mi] = 1.0f / v;
  }
  // redistribute: epilogue lane needs 1/sum for q = mi*16 + lq*4 + r,
  // held by lane (lq*4+r) (all lanes in its lq-group have the total).
  float inv[2][4];
#pragma unroll
  for (int mi = 0; mi < 2; ++mi)
#pragma unroll
    for (int r = 0; r < 4; ++r)
      inv[mi][r] = __shfl(linv[mi], lq * 4 + r);

#pragma unroll
  for (int mi = 0; mi < 2; ++mi)
#pragma unroll
    for (int di = 0; di < 4; ++di)
#pragma unroll
      for (int r = 0; r < 4; ++r)
        out[(size_t)(b * 2048 + q0 + mi * 16 + lq * 4 + r) * 1024 + h * 64 + di * 16 + lr] =
            f2b(acc_o[mi][di][r] * inv[mi][r]);
}

// ---------- launch ----------
// ws layout (112 MiB): T_a [0,8M) wt_qkv->wt_w1; T_b [8,16M) wt_proj->wt_w2;
// x2 bf16 [16,32M); Vt [32,48M); H [48,64M) h->o; qkv [64,112M);
// h3 [48,112M) overlays dead H+qkv; h2 bf16 in d_out scratch.
extern "C" void kernel_launch(void* const* d_in, const int* in_sizes, int n_in,
                              void* d_out, int out_size, void* d_ws, size_t ws_size,
                              hipStream_t stream) {
  (void)in_sizes; (void)n_in; (void)out_size; (void)ws_size;
  const float* x      = (const float*)d_in[0];
  const float* w_qkv  = (const float*)d_in[1];
  const float* w_proj = (const float*)d_in[2];
  const float* b_proj = (const float*)d_in[3];
  const float* ln1_g  = (const float*)d_in[4];
  const float* ln1_b  = (const float*)d_in[5];
  const float* w1     = (const float*)d_in[6];
  const float* b1     = (const float*)d_in[7];
  const float* w2     = (const float*)d_in[8];
  const float* b2     = (const float*)d_in[9];
  const float* ln2_g  = (const float*)d_in[10];
  const float* ln2_b  = (const float*)d_in[11];
  float* out = (float*)d_out;

  char* ws = (char*)d_ws;
  unsigned short* T_a   = (unsigned short*)(ws);
  unsigned short* T_b   = (unsigned short*)(ws + 8388608);
  unsigned short* x2buf = (unsigned short*)(ws + 16777216);   // bf16 [8192,1024]
  unsigned short* Vtbuf = (unsigned short*)(ws + 33554432);
  unsigned short* Hbuf  = (unsigned short*)(ws + 50331648);
  unsigned short* qkvb  = (unsigned short*)(ws + 67108864);
  unsigned short* h3buf = (unsigned short*)(ws + 50331648);
  unsigned short* h2buf = (unsigned short*)d_out;

  const dim3 tb(32, 8);
  transpose_k<<<dim3(96, 32),  tb, 0, stream>>>(w_qkv,  T_a, 1024, 3072);
  transpose_k<<<dim3(32, 32),  tb, 0, stream>>>(w_proj, T_b, 1024, 1024);
  // h = LN1(x)
  ln_kernel<<<8192, 256, 0, stream>>>(x, 0, ln1_g, ln1_b, Hbuf);
  // qkv = h @ w_qkv  (swap_xy=1)
  gemm_bt<<<dim3(64, 24), 256, 0, stream>>>(Hbuf, T_a, nullptr, nullptr, 0, qkvb, 8192, 3072, 1024, 0, 1, 1);
  transpose_k<<<dim3(128, 32), tb, 0, stream>>>(w1, T_a, 1024, 4096);
  // attention
  vt_k<<<dim3(8, 16, 4), 256, 0, stream>>>(qkvb, Vtbuf);
  attn_mfma<<<dim3(16, 16, 4), 256, 0, stream>>>(qkvb, Vtbuf, Hbuf);
  // x2 = o @ w_proj + b_proj + x  (bf16 out, swizzle)
  gemm_bt<<<dim3(64, 8), 256, 0, stream>>>(Hbuf, T_b, b_proj, x, 0, x2buf, 8192, 1024, 1024, 0, 1, 1);
  transpose_k<<<dim3(32, 128), tb, 0, stream>>>(w2, T_b, 4096, 1024);
  // h2 = LN2(x2)
  ln_kernel<<<8192, 256, 0, stream>>>(x2buf, 1, ln2_g, ln2_b, h2buf);
  // h3 = gelu(h2 @ w1 + b1)  (swap_xy=1)
  gemm_bt<<<dim3(64, 32), 256, 0, stream>>>(h2buf, T_a, b1, nullptr, 0, h3buf, 8192, 4096, 1024, 1, 1, 1);
  // out = h3 @ w2 + b2 + x2  (fp32 out, swizzle; direct epilogue)
  gemm_bt<<<dim3(64, 8), 256, 0, stream>>>(h3buf, T_b, b2, x2buf, 1, out, 8192, 1024, 4096, 0, 0, 1);
}

// Round 18
// 537.254 us; speedup vs baseline: 1.0456x; 1.0167x over previous
//
#include <hip/hip_runtime.h>
#include <cstdint>
#include <cstddef>

// ---------- types / helpers ----------
typedef float  v4f  __attribute__((ext_vector_type(4)));
typedef __bf16 v8bf __attribute__((ext_vector_type(8)));
typedef __bf16 v4bf __attribute__((ext_vector_type(4)));

__device__ __forceinline__ float b2f(unsigned short u) {
  union { unsigned int i; float f; } cv; cv.i = ((unsigned int)u) << 16; return cv.f;
}
__device__ __forceinline__ unsigned short f2b(float f) {
  union { float f; unsigned int i; } cv; cv.f = f;
  unsigned int i = cv.i;
  i += 0x7fffu + ((i >> 16) & 1u);      // round-to-nearest-even
  return (unsigned short)(i >> 16);
}
__device__ __forceinline__ unsigned short f2b_trunc(float f) {
  union { float f; unsigned int i; } cv; cv.f = f;
  return (unsigned short)(cv.i >> 16);  // truncate (cheap); P only
}
// raw v_exp_f32: D = 2^S0 (single trans-pipe instruction; __expf would add a v_mul)
__device__ __forceinline__ float exp2_raw(float x) {
  float r;
  asm("v_exp_f32 %0, %1" : "=v"(r) : "v"(x));
  return r;
}
// tanh-form GELU: x*sigmoid(1.59577*(x+0.044715x^3)); |err vs erf-GELU| <= ~3e-4.
__device__ __forceinline__ float gelu_fast(float x) {
  const float u = x * (1.5957691216f + 0.07135481627f * x * x);
  return x * (1.0f / (1.0f + __expf(-u)));
}
__device__ __forceinline__ void g2l16(const unsigned short* g, unsigned short* l) {
  __builtin_amdgcn_global_load_lds(
      (const __attribute__((address_space(1))) void*)g,
      (__attribute__((address_space(3))) void*)l,
      16, 0, 0);
}

// ---------- transpose + fp32->bf16 convert: in[R,C] f32 -> out[C,R] bf16 ----------
__global__ __launch_bounds__(256) void transpose_k(const float* __restrict__ in,
                                                   unsigned short* __restrict__ out,
                                                   int R, int C) {
  __shared__ float tile[32][33];
  const int tx = threadIdx.x, ty = threadIdx.y;
  const int r0 = blockIdx.y * 32, c0 = blockIdx.x * 32;
#pragma unroll
  for (int j = 0; j < 4; ++j)
    tile[ty + 8 * j][tx] = in[(size_t)(r0 + ty + 8 * j) * C + c0 + tx];
  __syncthreads();
#pragma unroll
  for (int j = 0; j < 4; ++j)
    out[(size_t)(c0 + ty + 8 * j) * R + r0 + tx] = f2b(tile[tx][ty + 8 * j]);
}

// ---------- layernorm over DIM=1024 (fp32 or bf16 in, bf16 out) ----------
__global__ __launch_bounds__(256) void ln_kernel(const void* __restrict__ xp, int in_bf16,
                                                 const float* __restrict__ g,
                                                 const float* __restrict__ bta,
                                                 unsigned short* __restrict__ out) {
  const int r = blockIdx.x, t = threadIdx.x;
  float v0, v1, v2, v3;
  if (in_bf16) {
    const ushort4 raw = *(const ushort4*)((const unsigned short*)xp + (size_t)r * 1024 + t * 4);
    v0 = b2f(raw.x); v1 = b2f(raw.y); v2 = b2f(raw.z); v3 = b2f(raw.w);
  } else {
    const float4 raw = *(const float4*)((const float*)xp + (size_t)r * 1024 + t * 4);
    v0 = raw.x; v1 = raw.y; v2 = raw.z; v3 = raw.w;
  }
  float s  = v0 + v1 + v2 + v3;
  float s2 = v0 * v0 + v1 * v1 + v2 * v2 + v3 * v3;
#pragma unroll
  for (int off = 32; off > 0; off >>= 1) {
    s  += __shfl_down(s, off);
    s2 += __shfl_down(s2, off);
  }
  __shared__ float red[8];
  const int w = t >> 6, lane = t & 63;
  if (lane == 0) { red[w] = s; red[4 + w] = s2; }
  __syncthreads();
  if (t == 0) {
    float ts = red[0] + red[1] + red[2] + red[3];
    float t2 = red[4] + red[5] + red[6] + red[7];
    float mu = ts * (1.0f / 1024.0f);
    float var = t2 * (1.0f / 1024.0f) - mu * mu;
    red[0] = mu;
    red[1] = rsqrtf(var + 1e-5f);
  }
  __syncthreads();
  const float mu = red[0], rs = red[1];
  const float4 graw = *(const float4*)(g + t * 4);
  const float4 braw = *(const float4*)(bta + t * 4);
  ushort4 o;
  o.x = f2b((v0 - mu) * rs * graw.x + braw.x);
  o.y = f2b((v1 - mu) * rs * graw.y + braw.y);
  o.z = f2b((v2 - mu) * rs * graw.z + braw.z);
  o.w = f2b((v3 - mu) * rs * graw.w + braw.w);
  *(ushort4*)(out + (size_t)r * 1024 + t * 4) = o;
}

// ---------- MFMA GEMM: C[M,N] = A[M,K] @ Bt[N,K]^T (+bias)(+gelu)(+res) ----------
// r17 verified config (546.2 total): BK=64, 2-buf dist-1 prefetch, counted
// vmcnt(8), chunk-XOR swizzle both-sides, (256,2), swap_xy grids.
// Epilogue: bf16 -> LDS-staged coalesced stores (measured -9% ffn1);
// fp32 -> direct stores (staged fp32 regressed, r16).
__global__ __launch_bounds__(256, 2) void gemm_bt(const unsigned short* __restrict__ A,
                                                  const unsigned short* __restrict__ Bt,
                                                  const float* __restrict__ bias,
                                                  const void* __restrict__ res, int res_bf16,
                                                  void* __restrict__ Cout,
                                                  int M, int N, int K, int act, int out_bf16,
                                                  int swap_xy) {
  __shared__ __align__(16) unsigned short shm[32768];   // 64KB: As[2]@0, Bs[2]@16384
  const int t = threadIdx.x;
  const int lane = t & 63, w = t >> 6;
  const int wr = (w >> 1) * 64, wc = (w & 1) * 64;
  const int lr = lane & 15, lq = lane >> 4;
  const int mb = swap_xy ? blockIdx.x : blockIdx.y;
  const int nb = swap_xy ? blockIdx.y : blockIdx.x;
  const int m0 = mb * 128, n0 = nb * 128;

  // staging: chunk c (0..1023) -> LDS linear (row=c>>3, chunk=c&7);
  // global source chunk = (c&7) ^ (row&7)  [both-sides swizzle]
  const unsigned short* Ag[4];
  const unsigned short* Bg[4];
#pragma unroll
  for (int j = 0; j < 4; ++j) {
    const int c = t + j * 256;
    const int row = c >> 3, ch = (c & 7) ^ (row & 7);
    Ag[j] = A  + (size_t)(m0 + row) * K + ch * 8;
    Bg[j] = Bt + (size_t)(n0 + row) * K + ch * 8;
  }

  v4f acc[4][4];
#pragma unroll
  for (int mi = 0; mi < 4; ++mi)
#pragma unroll
    for (int ni = 0; ni < 4; ++ni)
      acc[mi][ni] = (v4f){0.f, 0.f, 0.f, 0.f};

#define STAGE64(buf, ko)                                               \
  do {                                                                 \
    _Pragma("unroll")                                                  \
    for (int j = 0; j < 4; ++j) {                                      \
      g2l16(Ag[j] + (ko), shm + (buf) * 8192 + (t + j * 256) * 8);     \
      g2l16(Bg[j] + (ko), shm + 16384 + (buf) * 8192 + (t + j * 256) * 8); \
    }                                                                  \
  } while (0)

  const int nt = K >> 6;
  STAGE64(0, 0);

  for (int tt = 0; tt < nt; ++tt) {
    const int buf = tt & 1;
    if (tt + 1 < nt) {
      STAGE64(buf ^ 1, (tt + 1) << 6);
      // 8 just-issued loads (tile tt+1) stay in flight; tile tt guaranteed landed
      asm volatile("s_waitcnt vmcnt(8)" ::: "memory");
    } else {
      asm volatile("s_waitcnt vmcnt(0)" ::: "memory");
    }
    __builtin_amdgcn_s_barrier();
    asm volatile("" ::: "memory");

    const unsigned short* AsB = shm + buf * 8192;
    const unsigned short* BsB = shm + 16384 + buf * 8192;
#pragma unroll
    for (int kq = 0; kq < 2; ++kq) {
      const int ra = (((kq * 4 + lq) ^ (lr & 7)) << 3);   // swizzled read chunk
      v8bf af[4], bfr[4];
#pragma unroll
      for (int i = 0; i < 4; ++i) {
        af[i]  = *(const v8bf*)(AsB + (wr + i * 16 + lr) * 64 + ra);
        bfr[i] = *(const v8bf*)(BsB + (wc + i * 16 + lr) * 64 + ra);
      }
#pragma unroll
      for (int mi = 0; mi < 4; ++mi)
#pragma unroll
        for (int ni = 0; ni < 4; ++ni)
          acc[mi][ni] = __builtin_amdgcn_mfma_f32_16x16x32_bf16(af[mi], bfr[ni], acc[mi][ni], 0, 0, 0);
    }

    asm volatile("" ::: "memory");
    __builtin_amdgcn_s_barrier();
  }
#undef STAGE64

  if (out_bf16) {
    // ---- coalesced bf16 epilogue via dead staging LDS (measured -9% on ffn1) ----
    __syncthreads();
    unsigned short* Cs = shm;                 // [128][136] bf16, 34.8KB
#pragma unroll
    for (int mi = 0; mi < 4; ++mi) {
#pragma unroll
      for (int ni = 0; ni < 4; ++ni) {
        const int col = wc + ni * 16 + lr;
        const float bv = bias ? bias[n0 + col] : 0.0f;
#pragma unroll
        for (int r = 0; r < 4; ++r) {
          const int row = wr + mi * 16 + lq * 4 + r;
          float v = acc[mi][ni][r] + bv;
          if (act) v = gelu_fast(v);
          if (res) {
            v += res_bf16 ? b2f(((const unsigned short*)res)[(size_t)(m0 + row) * N + n0 + col])
                          : ((const float*)res)[(size_t)(m0 + row) * N + n0 + col];
          }
          Cs[row * 136 + col] = f2b(v);
        }
      }
    }
    __syncthreads();
    const int rr = t >> 3, ch = t & 7;
#pragma unroll
    for (int rb = 0; rb < 4; ++rb) {
      const int row = rb * 32 + rr;
#pragma unroll
      for (int j = 0; j < 2; ++j) {
        const int col = j * 64 + ch * 8;
        const uint4 val = *(const uint4*)(Cs + row * 136 + col);
        *(uint4*)((unsigned short*)Cout + (size_t)(m0 + row) * N + n0 + col) = val;
      }
    }
  } else {
    // ---- direct fp32 epilogue (r15-verified; staged version regressed) ----
#pragma unroll
    for (int mi = 0; mi < 4; ++mi) {
#pragma unroll
      for (int ni = 0; ni < 4; ++ni) {
        const int col = n0 + wc + ni * 16 + lr;
        const float bv = bias ? bias[col] : 0.0f;
#pragma unroll
        for (int r = 0; r < 4; ++r) {
          const int row = m0 + wr + mi * 16 + lq * 4 + r;
          float v = acc[mi][ni][r] + bv;
          if (act) v = gelu_fast(v);
          if (res) {
            v += res_bf16 ? b2f(((const unsigned short*)res)[(size_t)row * N + col])
                          : ((const float*)res)[(size_t)row * N + col];
          }
          ((float*)Cout)[(size_t)row * N + col] = v;
        }
      }
    }
  }
}

// ---------- V restage: qkv[token][3072] v-part -> Vt[(b*16+h)*64+d][2048 tokens] ----------
__global__ __launch_bounds__(256) void vt_k(const unsigned short* __restrict__ qkv,
                                            unsigned short* __restrict__ Vt) {
  const int t = threadIdx.x;
  const int n = blockIdx.x * 256 + t, h = blockIdx.y, b = blockIdx.z;
  const size_t src = (size_t)(b * 2048 + n) * 3072 + 2048 + h * 64;
  unsigned short v[64];
#pragma unroll
  for (int j = 0; j < 8; ++j)
    *(uint4*)(v + j * 8) = *(const uint4*)(qkv + src + j * 8);
  const size_t dstbase = ((size_t)(b * 16 + h) * 64) * 2048 + n;
#pragma unroll
  for (int d = 0; d < 64; ++d)
    Vt[dstbase + (size_t)d * 2048] = v[d];
}

// ---------- MFMA flash attention ----------
// r17 base (104.6 us) + THIS ROUND: (1) Q prescale folds log2(e) -> raw
// v_exp_f32 (D=2^S0, single trans op; deletes 32 v_mul/kt that __expf paid).
// Numerics validated by r11's run with the same prescale (absmax 0.03125).
// (2) lsum sums the f32 exp outputs directly (deletes 32 b2f shifts/kt);
// denominator differs from sum-of-truncated-P by <0.4% rel, inside tolerance.
__global__ __launch_bounds__(256, 3) void attn_mfma(const unsigned short* __restrict__ qkv,
                                                    const unsigned short* __restrict__ Vt,
                                                    unsigned short* __restrict__ out) {
  __shared__ __align__(16) unsigned short Ks[64 * 80];
  __shared__ __align__(16) unsigned short Vs[64 * 80];
  __shared__ __align__(16) unsigned short Ps[4][32 * 76];
  const int t = threadIdx.x;
  const int lane = t & 63, w = t >> 6;
  const int lr = lane & 15, lq = lane >> 4;
  const int h = blockIdx.x, b = blockIdx.z;
  const int q0 = blockIdx.y * 128 + w * 32;

  const float qscale = 0.125f * 1.4426950408889634f;  // 1/8 * log2(e)
  v8bf aq[2][2];
#pragma unroll
  for (int mi = 0; mi < 2; ++mi)
#pragma unroll
    for (int kq = 0; kq < 2; ++kq) {
      aq[mi][kq] = *(const v8bf*)(qkv + (size_t)(b * 2048 + q0 + mi * 16 + lr) * 3072
                                  + h * 64 + kq * 32 + lq * 8);
#pragma unroll
      for (int j = 0; j < 8; ++j)
        aq[mi][kq][j] = (__bf16)((float)aq[mi][kq][j] * qscale);
    }

  v4f acc_o[2][4];
  float lsum[2];
#pragma unroll
  for (int mi = 0; mi < 2; ++mi)
#pragma unroll
    for (int di = 0; di < 4; ++di)
      acc_o[mi][di] = (v4f){0.f, 0.f, 0.f, 0.f};
  lsum[0] = 0.0f; lsum[1] = 0.0f;

  // per-thread K/V staging addresses (2 chunks of 16B each)
  const int sc0 = t, sc1 = t + 256;
  const int kr0 = sc0 >> 3, ko0 = (sc0 & 7) * 8;
  const int kr1 = sc1 >> 3, ko1 = (sc1 & 7) * 8;
  const unsigned short* Kg0 = qkv + (size_t)(b * 2048 + kr0) * 3072 + 1024 + h * 64 + ko0;
  const unsigned short* Kg1 = qkv + (size_t)(b * 2048 + kr1) * 3072 + 1024 + h * 64 + ko1;
  const unsigned short* Vg0 = Vt + ((size_t)(b * 16 + h) * 64 + kr0) * 2048 + ko0;
  const unsigned short* Vg1 = Vt + ((size_t)(b * 16 + h) * 64 + kr1) * 2048 + ko1;

  // prologue: tile 0 into LDS
  uint4 kreg0 = *(const uint4*)(Kg0);
  uint4 kreg1 = *(const uint4*)(Kg1);
  uint4 vreg0 = *(const uint4*)(Vg0);
  uint4 vreg1 = *(const uint4*)(Vg1);
  *(uint4*)(Ks + kr0 * 80 + ko0) = kreg0;
  *(uint4*)(Ks + kr1 * 80 + ko1) = kreg1;
  *(uint4*)(Vs + kr0 * 80 + ko0) = vreg0;
  *(uint4*)(Vs + kr1 * 80 + ko1) = vreg1;
  __syncthreads();

  for (int kt = 0; kt < 32; ++kt) {
    // issue next tile's global loads early; latency hides under compute
    if (kt < 31) {
      const size_t kn = (size_t)(kt + 1) * 64;
      kreg0 = *(const uint4*)(Kg0 + kn * 3072);
      kreg1 = *(const uint4*)(Kg1 + kn * 3072);
      vreg0 = *(const uint4*)(Vg0 + kn);
      vreg1 = *(const uint4*)(Vg1 + kn);
    }

    // ---- QK^T, SWAPPED operands: D[k-row][q-col] ----
    v4f s_acc[2][4];
#pragma unroll
    for (int mi = 0; mi < 2; ++mi)
#pragma unroll
      for (int ni = 0; ni < 4; ++ni)
        s_acc[mi][ni] = (v4f){0.f, 0.f, 0.f, 0.f};
#pragma unroll
    for (int kq = 0; kq < 2; ++kq) {
      v8bf bk[4];
#pragma unroll
      for (int ni = 0; ni < 4; ++ni)
        bk[ni] = *(const v8bf*)(Ks + (ni * 16 + lr) * 80 + kq * 32 + lq * 8);
      __builtin_amdgcn_s_setprio(1);
#pragma unroll
      for (int mi = 0; mi < 2; ++mi)
#pragma unroll
        for (int ni = 0; ni < 4; ++ni)
          s_acc[mi][ni] = __builtin_amdgcn_mfma_f32_16x16x32_bf16(bk[ni], aq[mi][kq], s_acc[mi][ni], 0, 0, 0);
      __builtin_amdgcn_s_setprio(0);
    }

    // ---- softmax: P = 2^(S'); lane holds P[q=lr][k=ni*16+lq*4+r] ----
#pragma unroll
    for (int mi = 0; mi < 2; ++mi)
#pragma unroll
      for (int ni = 0; ni < 4; ++ni) {
        const float p0 = exp2_raw(s_acc[mi][ni][0]);
        const float p1 = exp2_raw(s_acc[mi][ni][1]);
        const float p2 = exp2_raw(s_acc[mi][ni][2]);
        const float p3 = exp2_raw(s_acc[mi][ni][3]);
        lsum[mi] += (p0 + p1) + (p2 + p3);
        ushort4 pk;
        pk.x = f2b_trunc(p0); pk.y = f2b_trunc(p1);
        pk.z = f2b_trunc(p2); pk.w = f2b_trunc(p3);
        *(ushort4*)(Ps[w] + (mi * 16 + lr) * 76 + ni * 16 + lq * 4) = pk;
      }

    // ---- P @ V (reads unchanged: P[q][k] row-major, stride 76) ----
#pragma unroll
    for (int ks = 0; ks < 2; ++ks) {
      v8bf ap[2], bv[4];
#pragma unroll
      for (int mi = 0; mi < 2; ++mi) {
        const unsigned short* base = Ps[w] + (mi * 16 + lr) * 76 + ks * 32 + lq * 8;
        const v4bf lo = *(const v4bf*)(base);
        const v4bf hi = *(const v4bf*)(base + 4);
        ap[mi] = __builtin_shufflevector(lo, hi, 0, 1, 2, 3, 4, 5, 6, 7);
      }
#pragma unroll
      for (int di = 0; di < 4; ++di)
        bv[di] = *(const v8bf*)(Vs + (di * 16 + lr) * 80 + ks * 32 + lq * 8);
      __builtin_amdgcn_s_setprio(1);
#pragma unroll
      for (int mi = 0; mi < 2; ++mi)
#pragma unroll
        for (int di = 0; di < 4; ++di)
          acc_o[mi][di] = __builtin_amdgcn_mfma_f32_16x16x32_bf16(ap[mi], bv[di], acc_o[mi][di], 0, 0, 0);
      __builtin_amdgcn_s_setprio(0);
    }

    __syncthreads();            // all waves done reading Ks/Vs
    if (kt < 31) {
      *(uint4*)(Ks + kr0 * 80 + ko0) = kreg0;
      *(uint4*)(Ks + kr1 * 80 + ko1) = kreg1;
      *(uint4*)(Vs + kr0 * 80 + ko0) = vreg0;
      *(uint4*)(Vs + kr1 * 80 + ko1) = vreg1;
    }
    __syncthreads();            // next tile visible
  }

  // lsum[mi] holds partial sum over k for q = mi*16 + lr, spread across lq group.
  float linv[2];
#pragma unroll
  for (int mi = 0; mi < 2; ++mi) {
    float v = lsum[mi];
    v += __shfl_xor(v, 16);
    v += __shfl_xor(v, 32);
    linv[mi] = 1.0f / v;
  }
  // redistribute: epilogue lane needs 1/sum for q = mi*16 + lq*4 + r,
  // held by lane (lq*4+r) (all lanes in its lq-group have the total).
  float inv[2][4];
#pragma unroll
  for (int mi = 0; mi < 2; ++mi)
#pragma unroll
    for (int r = 0; r < 4; ++r)
      inv[mi][r] = __shfl(linv[mi], lq * 4 + r);

#pragma unroll
  for (int mi = 0; mi < 2; ++mi)
#pragma unroll
    for (int di = 0; di < 4; ++di)
#pragma unroll
      for (int r = 0; r < 4; ++r)
        out[(size_t)(b * 2048 + q0 + mi * 16 + lq * 4 + r) * 1024 + h * 64 + di * 16 + lr] =
            f2b(acc_o[mi][di][r] * inv[mi][r]);
}

// ---------- launch ----------
// ws layout (112 MiB): T_a [0,8M) wt_qkv->wt_w1; T_b [8,16M) wt_proj->wt_w2;
// x2 bf16 [16,32M); Vt [32,48M); H [48,64M) h->o; qkv [64,112M);
// h3 [48,112M) overlays dead H+qkv; h2 bf16 in d_out scratch.
extern "C" void kernel_launch(void* const* d_in, const int* in_sizes, int n_in,
                              void* d_out, int out_size, void* d_ws, size_t ws_size,
                              hipStream_t stream) {
  (void)in_sizes; (void)n_in; (void)out_size; (void)ws_size;
  const float* x      = (const float*)d_in[0];
  const float* w_qkv  = (const float*)d_in[1];
  const float* w_proj = (const float*)d_in[2];
  const float* b_proj = (const float*)d_in[3];
  const float* ln1_g  = (const float*)d_in[4];
  const float* ln1_b  = (const float*)d_in[5];
  const float* w1     = (const float*)d_in[6];
  const float* b1     = (const float*)d_in[7];
  const float* w2     = (const float*)d_in[8];
  const float* b2     = (const float*)d_in[9];
  const float* ln2_g  = (const float*)d_in[10];
  const float* ln2_b  = (const float*)d_in[11];
  float* out = (float*)d_out;

  char* ws = (char*)d_ws;
  unsigned short* T_a   = (unsigned short*)(ws);
  unsigned short* T_b   = (unsigned short*)(ws + 8388608);
  unsigned short* x2buf = (unsigned short*)(ws + 16777216);   // bf16 [8192,1024]
  unsigned short* Vtbuf = (unsigned short*)(ws + 33554432);
  unsigned short* Hbuf  = (unsigned short*)(ws + 50331648);
  unsigned short* qkvb  = (unsigned short*)(ws + 67108864);
  unsigned short* h3buf = (unsigned short*)(ws + 50331648);
  unsigned short* h2buf = (unsigned short*)d_out;

  const dim3 tb(32, 8);
  transpose_k<<<dim3(96, 32),  tb, 0, stream>>>(w_qkv,  T_a, 1024, 3072);
  transpose_k<<<dim3(32, 32),  tb, 0, stream>>>(w_proj, T_b, 1024, 1024);
  // h = LN1(x)
  ln_kernel<<<8192, 256, 0, stream>>>(x, 0, ln1_g, ln1_b, Hbuf);
  // qkv = h @ w_qkv  (swap_xy=1)
  gemm_bt<<<dim3(64, 24), 256, 0, stream>>>(Hbuf, T_a, nullptr, nullptr, 0, qkvb, 8192, 3072, 1024, 0, 1, 1);
  transpose_k<<<dim3(128, 32), tb, 0, stream>>>(w1, T_a, 1024, 4096);
  // attention
  vt_k<<<dim3(8, 16, 4), 256, 0, stream>>>(qkvb, Vtbuf);
  attn_mfma<<<dim3(16, 16, 4), 256, 0, stream>>>(qkvb, Vtbuf, Hbuf);
  // x2 = o @ w_proj + b_proj + x  (bf16 out, swizzle)
  gemm_bt<<<dim3(64, 8), 256, 0, stream>>>(Hbuf, T_b, b_proj, x, 0, x2buf, 8192, 1024, 1024, 0, 1, 1);
  transpose_k<<<dim3(32, 128), tb, 0, stream>>>(w2, T_b, 4096, 1024);
  // h2 = LN2(x2)
  ln_kernel<<<8192, 256, 0, stream>>>(x2buf, 1, ln2_g, ln2_b, h2buf);
  // h3 = gelu(h2 @ w1 + b1)  (swap_xy=1)
  gemm_bt<<<dim3(64, 32), 256, 0, stream>>>(h2buf, T_a, b1, nullptr, 0, h3buf, 8192, 4096, 1024, 1, 1, 1);
  // out = h3 @ w2 + b2 + x2  (fp32 out, swizzle; direct epilogue)
  gemm_bt<<<dim3(64, 8), 256, 0, stream>>>(h3buf, T_b, b2, x2buf, 1, out, 8192, 1024, 4096, 0, 0, 1);
}

// Round 19
// 505.863 us; speedup vs baseline: 1.1104x; 1.0621x over previous
//
#include <hip/hip_runtime.h>
#include <cstdint>
#include <cstddef>

// ---------- types / helpers ----------
typedef float  v4f  __attribute__((ext_vector_type(4)));
typedef __bf16 v8bf __attribute__((ext_vector_type(8)));
typedef __bf16 v4bf __attribute__((ext_vector_type(4)));

__device__ __forceinline__ float b2f(unsigned short u) {
  union { unsigned int i; float f; } cv; cv.i = ((unsigned int)u) << 16; return cv.f;
}
__device__ __forceinline__ unsigned short f2b(float f) {
  union { float f; unsigned int i; } cv; cv.f = f;
  unsigned int i = cv.i;
  i += 0x7fffu + ((i >> 16) & 1u);      // round-to-nearest-even
  return (unsigned short)(i >> 16);
}
__device__ __forceinline__ unsigned short f2b_trunc(float f) {
  union { float f; unsigned int i; } cv; cv.f = f;
  return (unsigned short)(cv.i >> 16);  // truncate (cheap); P only
}
// raw v_exp_f32: D = 2^S0 (single trans-pipe instruction; __expf would add a v_mul)
__device__ __forceinline__ float exp2_raw(float x) {
  float r;
  asm("v_exp_f32 %0, %1" : "=v"(r) : "v"(x));
  return r;
}
// tanh-form GELU: x*sigmoid(1.59577*(x+0.044715x^3)); |err vs erf-GELU| <= ~3e-4.
__device__ __forceinline__ float gelu_fast(float x) {
  const float u = x * (1.5957691216f + 0.07135481627f * x * x);
  return x * (1.0f / (1.0f + __expf(-u)));
}
__device__ __forceinline__ void g2l16(const unsigned short* g, unsigned short* l) {
  __builtin_amdgcn_global_load_lds(
      (const __attribute__((address_space(1))) void*)g,
      (__attribute__((address_space(3))) void*)l,
      16, 0, 0);
}

// ---------- transpose + fp32->bf16 convert: in[R,C] f32 -> out[C,R] bf16 ----------
__global__ __launch_bounds__(256) void transpose_k(const float* __restrict__ in,
                                                   unsigned short* __restrict__ out,
                                                   int R, int C) {
  __shared__ float tile[32][33];
  const int tx = threadIdx.x, ty = threadIdx.y;
  const int r0 = blockIdx.y * 32, c0 = blockIdx.x * 32;
#pragma unroll
  for (int j = 0; j < 4; ++j)
    tile[ty + 8 * j][tx] = in[(size_t)(r0 + ty + 8 * j) * C + c0 + tx];
  __syncthreads();
#pragma unroll
  for (int j = 0; j < 4; ++j)
    out[(size_t)(c0 + ty + 8 * j) * R + r0 + tx] = f2b(tile[tx][ty + 8 * j]);
}

// ---------- layernorm over DIM=1024 (fp32 or bf16 in, bf16 out) ----------
__global__ __launch_bounds__(256) void ln_kernel(const void* __restrict__ xp, int in_bf16,
                                                 const float* __restrict__ g,
                                                 const float* __restrict__ bta,
                                                 unsigned short* __restrict__ out) {
  const int r = blockIdx.x, t = threadIdx.x;
  float v0, v1, v2, v3;
  if (in_bf16) {
    const ushort4 raw = *(const ushort4*)((const unsigned short*)xp + (size_t)r * 1024 + t * 4);
    v0 = b2f(raw.x); v1 = b2f(raw.y); v2 = b2f(raw.z); v3 = b2f(raw.w);
  } else {
    const float4 raw = *(const float4*)((const float*)xp + (size_t)r * 1024 + t * 4);
    v0 = raw.x; v1 = raw.y; v2 = raw.z; v3 = raw.w;
  }
  float s  = v0 + v1 + v2 + v3;
  float s2 = v0 * v0 + v1 * v1 + v2 * v2 + v3 * v3;
#pragma unroll
  for (int off = 32; off > 0; off >>= 1) {
    s  += __shfl_down(s, off);
    s2 += __shfl_down(s2, off);
  }
  __shared__ float red[8];
  const int w = t >> 6, lane = t & 63;
  if (lane == 0) { red[w] = s; red[4 + w] = s2; }
  __syncthreads();
  if (t == 0) {
    float ts = red[0] + red[1] + red[2] + red[3];
    float t2 = red[4] + red[5] + red[6] + red[7];
    float mu = ts * (1.0f / 1024.0f);
    float var = t2 * (1.0f / 1024.0f) - mu * mu;
    red[0] = mu;
    red[1] = rsqrtf(var + 1e-5f);
  }
  __syncthreads();
  const float mu = red[0], rs = red[1];
  const float4 graw = *(const float4*)(g + t * 4);
  const float4 braw = *(const float4*)(bta + t * 4);
  ushort4 o;
  o.x = f2b((v0 - mu) * rs * graw.x + braw.x);
  o.y = f2b((v1 - mu) * rs * graw.y + braw.y);
  o.z = f2b((v2 - mu) * rs * graw.z + braw.z);
  o.w = f2b((v3 - mu) * rs * graw.w + braw.w);
  *(ushort4*)(out + (size_t)r * 1024 + t * 4) = o;
}

// ---------- MFMA GEMM: C[M,N] = A[M,K] @ Bt[N,K]^T (+bias)(+gelu)(+res) ----------
// r18 verified config (537.3 total): BK=64, 2-buf dist-1 prefetch, counted
// vmcnt(8), chunk-XOR swizzle both-sides, (256,2), swap_xy grids.
// Epilogue: bf16 -> LDS-staged coalesced stores; fp32 -> direct stores.
__global__ __launch_bounds__(256, 2) void gemm_bt(const unsigned short* __restrict__ A,
                                                  const unsigned short* __restrict__ Bt,
                                                  const float* __restrict__ bias,
                                                  const void* __restrict__ res, int res_bf16,
                                                  void* __restrict__ Cout,
                                                  int M, int N, int K, int act, int out_bf16,
                                                  int swap_xy) {
  __shared__ __align__(16) unsigned short shm[32768];   // 64KB: As[2]@0, Bs[2]@16384
  const int t = threadIdx.x;
  const int lane = t & 63, w = t >> 6;
  const int wr = (w >> 1) * 64, wc = (w & 1) * 64;
  const int lr = lane & 15, lq = lane >> 4;
  const int mb = swap_xy ? blockIdx.x : blockIdx.y;
  const int nb = swap_xy ? blockIdx.y : blockIdx.x;
  const int m0 = mb * 128, n0 = nb * 128;

  // staging: chunk c (0..1023) -> LDS linear (row=c>>3, chunk=c&7);
  // global source chunk = (c&7) ^ (row&7)  [both-sides swizzle]
  const unsigned short* Ag[4];
  const unsigned short* Bg[4];
#pragma unroll
  for (int j = 0; j < 4; ++j) {
    const int c = t + j * 256;
    const int row = c >> 3, ch = (c & 7) ^ (row & 7);
    Ag[j] = A  + (size_t)(m0 + row) * K + ch * 8;
    Bg[j] = Bt + (size_t)(n0 + row) * K + ch * 8;
  }

  v4f acc[4][4];
#pragma unroll
  for (int mi = 0; mi < 4; ++mi)
#pragma unroll
    for (int ni = 0; ni < 4; ++ni)
      acc[mi][ni] = (v4f){0.f, 0.f, 0.f, 0.f};

#define STAGE64(buf, ko)                                               \
  do {                                                                 \
    _Pragma("unroll")                                                  \
    for (int j = 0; j < 4; ++j) {                                      \
      g2l16(Ag[j] + (ko), shm + (buf) * 8192 + (t + j * 256) * 8);     \
      g2l16(Bg[j] + (ko), shm + 16384 + (buf) * 8192 + (t + j * 256) * 8); \
    }                                                                  \
  } while (0)

  const int nt = K >> 6;
  STAGE64(0, 0);

  for (int tt = 0; tt < nt; ++tt) {
    const int buf = tt & 1;
    if (tt + 1 < nt) {
      STAGE64(buf ^ 1, (tt + 1) << 6);
      // 8 just-issued loads (tile tt+1) stay in flight; tile tt guaranteed landed
      asm volatile("s_waitcnt vmcnt(8)" ::: "memory");
    } else {
      asm volatile("s_waitcnt vmcnt(0)" ::: "memory");
    }
    __builtin_amdgcn_s_barrier();
    asm volatile("" ::: "memory");

    const unsigned short* AsB = shm + buf * 8192;
    const unsigned short* BsB = shm + 16384 + buf * 8192;
#pragma unroll
    for (int kq = 0; kq < 2; ++kq) {
      const int ra = (((kq * 4 + lq) ^ (lr & 7)) << 3);   // swizzled read chunk
      v8bf af[4], bfr[4];
#pragma unroll
      for (int i = 0; i < 4; ++i) {
        af[i]  = *(const v8bf*)(AsB + (wr + i * 16 + lr) * 64 + ra);
        bfr[i] = *(const v8bf*)(BsB + (wc + i * 16 + lr) * 64 + ra);
      }
#pragma unroll
      for (int mi = 0; mi < 4; ++mi)
#pragma unroll
        for (int ni = 0; ni < 4; ++ni)
          acc[mi][ni] = __builtin_amdgcn_mfma_f32_16x16x32_bf16(af[mi], bfr[ni], acc[mi][ni], 0, 0, 0);
    }

    asm volatile("" ::: "memory");
    __builtin_amdgcn_s_barrier();
  }
#undef STAGE64

  if (out_bf16) {
    // ---- coalesced bf16 epilogue via dead staging LDS (measured -9% on ffn1) ----
    __syncthreads();
    unsigned short* Cs = shm;                 // [128][136] bf16, 34.8KB
#pragma unroll
    for (int mi = 0; mi < 4; ++mi) {
#pragma unroll
      for (int ni = 0; ni < 4; ++ni) {
        const int col = wc + ni * 16 + lr;
        const float bv = bias ? bias[n0 + col] : 0.0f;
#pragma unroll
        for (int r = 0; r < 4; ++r) {
          const int row = wr + mi * 16 + lq * 4 + r;
          float v = acc[mi][ni][r] + bv;
          if (act) v = gelu_fast(v);
          if (res) {
            v += res_bf16 ? b2f(((const unsigned short*)res)[(size_t)(m0 + row) * N + n0 + col])
                          : ((const float*)res)[(size_t)(m0 + row) * N + n0 + col];
          }
          Cs[row * 136 + col] = f2b(v);
        }
      }
    }
    __syncthreads();
    const int rr = t >> 3, ch = t & 7;
#pragma unroll
    for (int rb = 0; rb < 4; ++rb) {
      const int row = rb * 32 + rr;
#pragma unroll
      for (int j = 0; j < 2; ++j) {
        const int col = j * 64 + ch * 8;
        const uint4 val = *(const uint4*)(Cs + row * 136 + col);
        *(uint4*)((unsigned short*)Cout + (size_t)(m0 + row) * N + n0 + col) = val;
      }
    }
  } else {
    // ---- direct fp32 epilogue (r15-verified; staged version regressed) ----
#pragma unroll
    for (int mi = 0; mi < 4; ++mi) {
#pragma unroll
      for (int ni = 0; ni < 4; ++ni) {
        const int col = n0 + wc + ni * 16 + lr;
        const float bv = bias ? bias[col] : 0.0f;
#pragma unroll
        for (int r = 0; r < 4; ++r) {
          const int row = m0 + wr + mi * 16 + lq * 4 + r;
          float v = acc[mi][ni][r] + bv;
          if (act) v = gelu_fast(v);
          if (res) {
            v += res_bf16 ? b2f(((const unsigned short*)res)[(size_t)row * N + col])
                          : ((const float*)res)[(size_t)row * N + col];
          }
          ((float*)Cout)[(size_t)row * N + col] = v;
        }
      }
    }
  }
}

// ---------- V restage: qkv[token][3072] v-part -> Vt[(b*16+h)*64+d][2048 tokens] ----------
__global__ __launch_bounds__(256) void vt_k(const unsigned short* __restrict__ qkv,
                                            unsigned short* __restrict__ Vt) {
  const int t = threadIdx.x;
  const int n = blockIdx.x * 256 + t, h = blockIdx.y, b = blockIdx.z;
  const size_t src = (size_t)(b * 2048 + n) * 3072 + 2048 + h * 64;
  unsigned short v[64];
#pragma unroll
  for (int j = 0; j < 8; ++j)
    *(uint4*)(v + j * 8) = *(const uint4*)(qkv + src + j * 8);
  const size_t dstbase = ((size_t)(b * 16 + h) * 64) * 2048 + n;
#pragma unroll
  for (int d = 0; d < 64; ++d)
    Vt[dstbase + (size_t)d * 2048] = v[d];
}

// ---------- MFMA flash attention ----------
// r18 base (~105 us) + THIS ROUND: per-warp q-tile 32->64 rows (MI=4).
// Same logic that made BK=64 pay on GEMM: K/V staging, barriers, and vmcnt
// waits are fixed per kt per block; doubling q-rows/warp halves them per
// output and halves K/V global re-reads (FETCH 24.6 -> ~14 MB).
// Registers: persistent ~132 (aq 32 + acc_o 64 + kreg/vreg 16 + addr 20),
// peak +s_acc 64 +bk 16 ~= 212 <= 256 cap at (256,2); occupancy was already
// effectively 2 blocks/CU. LDS: Ks+Vs 20KB + Ps 4x64x76x2B = 38.9KB -> 59.4KB.
__global__ __launch_bounds__(256, 2) void attn_mfma(const unsigned short* __restrict__ qkv,
                                                    const unsigned short* __restrict__ Vt,
                                                    unsigned short* __restrict__ out) {
  __shared__ __align__(16) unsigned short Ks[64 * 80];
  __shared__ __align__(16) unsigned short Vs[64 * 80];
  __shared__ __align__(16) unsigned short Ps[4][64 * 76];
  const int t = threadIdx.x;
  const int lane = t & 63, w = t >> 6;
  const int lr = lane & 15, lq = lane >> 4;
  const int h = blockIdx.x, b = blockIdx.z;
  const int q0 = blockIdx.y * 256 + w * 64;

  const float qscale = 0.125f * 1.4426950408889634f;  // 1/8 * log2(e)
  v8bf aq[4][2];
#pragma unroll
  for (int mi = 0; mi < 4; ++mi)
#pragma unroll
    for (int kq = 0; kq < 2; ++kq) {
      aq[mi][kq] = *(const v8bf*)(qkv + (size_t)(b * 2048 + q0 + mi * 16 + lr) * 3072
                                  + h * 64 + kq * 32 + lq * 8);
#pragma unroll
      for (int j = 0; j < 8; ++j)
        aq[mi][kq][j] = (__bf16)((float)aq[mi][kq][j] * qscale);
    }

  v4f acc_o[4][4];
  float lsum[4];
#pragma unroll
  for (int mi = 0; mi < 4; ++mi) {
#pragma unroll
    for (int di = 0; di < 4; ++di)
      acc_o[mi][di] = (v4f){0.f, 0.f, 0.f, 0.f};
    lsum[mi] = 0.0f;
  }

  // per-thread K/V staging addresses (2 chunks of 16B each)
  const int sc0 = t, sc1 = t + 256;
  const int kr0 = sc0 >> 3, ko0 = (sc0 & 7) * 8;
  const int kr1 = sc1 >> 3, ko1 = (sc1 & 7) * 8;
  const unsigned short* Kg0 = qkv + (size_t)(b * 2048 + kr0) * 3072 + 1024 + h * 64 + ko0;
  const unsigned short* Kg1 = qkv + (size_t)(b * 2048 + kr1) * 3072 + 1024 + h * 64 + ko1;
  const unsigned short* Vg0 = Vt + ((size_t)(b * 16 + h) * 64 + kr0) * 2048 + ko0;
  const unsigned short* Vg1 = Vt + ((size_t)(b * 16 + h) * 64 + kr1) * 2048 + ko1;

  // prologue: tile 0 into LDS
  uint4 kreg0 = *(const uint4*)(Kg0);
  uint4 kreg1 = *(const uint4*)(Kg1);
  uint4 vreg0 = *(const uint4*)(Vg0);
  uint4 vreg1 = *(const uint4*)(Vg1);
  *(uint4*)(Ks + kr0 * 80 + ko0) = kreg0;
  *(uint4*)(Ks + kr1 * 80 + ko1) = kreg1;
  *(uint4*)(Vs + kr0 * 80 + ko0) = vreg0;
  *(uint4*)(Vs + kr1 * 80 + ko1) = vreg1;
  __syncthreads();

  for (int kt = 0; kt < 32; ++kt) {
    // issue next tile's global loads early; latency hides under compute
    if (kt < 31) {
      const size_t kn = (size_t)(kt + 1) * 64;
      kreg0 = *(const uint4*)(Kg0 + kn * 3072);
      kreg1 = *(const uint4*)(Kg1 + kn * 3072);
      vreg0 = *(const uint4*)(Vg0 + kn);
      vreg1 = *(const uint4*)(Vg1 + kn);
    }

    // ---- QK^T, SWAPPED operands: D[k-row][q-col] ----
    v4f s_acc[4][4];
#pragma unroll
    for (int mi = 0; mi < 4; ++mi)
#pragma unroll
      for (int ni = 0; ni < 4; ++ni)
        s_acc[mi][ni] = (v4f){0.f, 0.f, 0.f, 0.f};
#pragma unroll
    for (int kq = 0; kq < 2; ++kq) {
      v8bf bk[4];
#pragma unroll
      for (int ni = 0; ni < 4; ++ni)
        bk[ni] = *(const v8bf*)(Ks + (ni * 16 + lr) * 80 + kq * 32 + lq * 8);
      __builtin_amdgcn_s_setprio(1);
#pragma unroll
      for (int mi = 0; mi < 4; ++mi)
#pragma unroll
        for (int ni = 0; ni < 4; ++ni)
          s_acc[mi][ni] = __builtin_amdgcn_mfma_f32_16x16x32_bf16(bk[ni], aq[mi][kq], s_acc[mi][ni], 0, 0, 0);
      __builtin_amdgcn_s_setprio(0);
    }

    // ---- softmax: P = 2^(S'); lane holds P[q=lr][k=ni*16+lq*4+r] ----
#pragma unroll
    for (int mi = 0; mi < 4; ++mi)
#pragma unroll
      for (int ni = 0; ni < 4; ++ni) {
        const float p0 = exp2_raw(s_acc[mi][ni][0]);
        const float p1 = exp2_raw(s_acc[mi][ni][1]);
        const float p2 = exp2_raw(s_acc[mi][ni][2]);
        const float p3 = exp2_raw(s_acc[mi][ni][3]);
        lsum[mi] += (p0 + p1) + (p2 + p3);
        ushort4 pk;
        pk.x = f2b_trunc(p0); pk.y = f2b_trunc(p1);
        pk.z = f2b_trunc(p2); pk.w = f2b_trunc(p3);
        *(ushort4*)(Ps[w] + (mi * 16 + lr) * 76 + ni * 16 + lq * 4) = pk;
      }

    // ---- P @ V (P[q][k] row-major, stride 76) ----
#pragma unroll
    for (int ks = 0; ks < 2; ++ks) {
      v8bf ap[4], bv[4];
#pragma unroll
      for (int mi = 0; mi < 4; ++mi) {
        const unsigned short* base = Ps[w] + (mi * 16 + lr) * 76 + ks * 32 + lq * 8;
        const v4bf lo = *(const v4bf*)(base);
        const v4bf hi = *(const v4bf*)(base + 4);
        ap[mi] = __builtin_shufflevector(lo, hi, 0, 1, 2, 3, 4, 5, 6, 7);
      }
#pragma unroll
      for (int di = 0; di < 4; ++di)
        bv[di] = *(const v8bf*)(Vs + (di * 16 + lr) * 80 + ks * 32 + lq * 8);
      __builtin_amdgcn_s_setprio(1);
#pragma unroll
      for (int mi = 0; mi < 4; ++mi)
#pragma unroll
        for (int di = 0; di < 4; ++di)
          acc_o[mi][di] = __builtin_amdgcn_mfma_f32_16x16x32_bf16(ap[mi], bv[di], acc_o[mi][di], 0, 0, 0);
      __builtin_amdgcn_s_setprio(0);
    }

    __syncthreads();            // all waves done reading Ks/Vs
    if (kt < 31) {
      *(uint4*)(Ks + kr0 * 80 + ko0) = kreg0;
      *(uint4*)(Ks + kr1 * 80 + ko1) = kreg1;
      *(uint4*)(Vs + kr0 * 80 + ko0) = vreg0;
      *(uint4*)(Vs + kr1 * 80 + ko1) = vreg1;
    }
    __syncthreads();            // next tile visible
  }

  // lsum[mi] holds partial sum over k for q = mi*16 + lr, spread across lq group.
  float linv[4];
#pragma unroll
  for (int mi = 0; mi < 4; ++mi) {
    float v = lsum[mi];
    v += __shfl_xor(v, 16);
    v += __shfl_xor(v, 32);
    linv[mi] = 1.0f / v;
  }
  // redistribute: epilogue lane needs 1/sum for q = mi*16 + lq*4 + r,
  // held by lane (lq*4+r) (all lanes in its lq-group have the total).
  float inv[4][4];
#pragma unroll
  for (int mi = 0; mi < 4; ++mi)
#pragma unroll
    for (int r = 0; r < 4; ++r)
      inv[mi][r] = __shfl(linv[mi], lq * 4 + r);

#pragma unroll
  for (int mi = 0; mi < 4; ++mi)
#pragma unroll
    for (int di = 0; di < 4; ++di)
#pragma unroll
      for (int r = 0; r < 4; ++r)
        out[(size_t)(b * 2048 + q0 + mi * 16 + lq * 4 + r) * 1024 + h * 64 + di * 16 + lr] =
            f2b(acc_o[mi][di][r] * inv[mi][r]);
}

// ---------- launch ----------
// ws layout (112 MiB): T_a [0,8M) wt_qkv->wt_w1; T_b [8,16M) wt_proj->wt_w2;
// x2 bf16 [16,32M); Vt [32,48M); H [48,64M) h->o; qkv [64,112M);
// h3 [48,112M) overlays dead H+qkv; h2 bf16 in d_out scratch.
extern "C" void kernel_launch(void* const* d_in, const int* in_sizes, int n_in,
                              void* d_out, int out_size, void* d_ws, size_t ws_size,
                              hipStream_t stream) {
  (void)in_sizes; (void)n_in; (void)out_size; (void)ws_size;
  const float* x      = (const float*)d_in[0];
  const float* w_qkv  = (const float*)d_in[1];
  const float* w_proj = (const float*)d_in[2];
  const float* b_proj = (const float*)d_in[3];
  const float* ln1_g  = (const float*)d_in[4];
  const float* ln1_b  = (const float*)d_in[5];
  const float* w1     = (const float*)d_in[6];
  const float* b1     = (const float*)d_in[7];
  const float* w2     = (const float*)d_in[8];
  const float* b2     = (const float*)d_in[9];
  const float* ln2_g  = (const float*)d_in[10];
  const float* ln2_b  = (const float*)d_in[11];
  float* out = (float*)d_out;

  char* ws = (char*)d_ws;
  unsigned short* T_a   = (unsigned short*)(ws);
  unsigned short* T_b   = (unsigned short*)(ws + 8388608);
  unsigned short* x2buf = (unsigned short*)(ws + 16777216);   // bf16 [8192,1024]
  unsigned short* Vtbuf = (unsigned short*)(ws + 33554432);
  unsigned short* Hbuf  = (unsigned short*)(ws + 50331648);
  unsigned short* qkvb  = (unsigned short*)(ws + 67108864);
  unsigned short* h3buf = (unsigned short*)(ws + 50331648);
  unsigned short* h2buf = (unsigned short*)d_out;

  const dim3 tb(32, 8);
  transpose_k<<<dim3(96, 32),  tb, 0, stream>>>(w_qkv,  T_a, 1024, 3072);
  transpose_k<<<dim3(32, 32),  tb, 0, stream>>>(w_proj, T_b, 1024, 1024);
  // h = LN1(x)
  ln_kernel<<<8192, 256, 0, stream>>>(x, 0, ln1_g, ln1_b, Hbuf);
  // qkv = h @ w_qkv  (swap_xy=1)
  gemm_bt<<<dim3(64, 24), 256, 0, stream>>>(Hbuf, T_a, nullptr, nullptr, 0, qkvb, 8192, 3072, 1024, 0, 1, 1);
  transpose_k<<<dim3(128, 32), tb, 0, stream>>>(w1, T_a, 1024, 4096);
  // attention  (q-tile 256 rows/block: grid y = 2048/256 = 8)
  vt_k<<<dim3(8, 16, 4), 256, 0, stream>>>(qkvb, Vtbuf);
  attn_mfma<<<dim3(16, 8, 4), 256, 0, stream>>>(qkvb, Vtbuf, Hbuf);
  // x2 = o @ w_proj + b_proj + x  (bf16 out, swizzle)
  gemm_bt<<<dim3(64, 8), 256, 0, stream>>>(Hbuf, T_b, b_proj, x, 0, x2buf, 8192, 1024, 1024, 0, 1, 1);
  transpose_k<<<dim3(32, 128), tb, 0, stream>>>(w2, T_b, 4096, 1024);
  // h2 = LN2(x2)
  ln_kernel<<<8192, 256, 0, stream>>>(x2buf, 1, ln2_g, ln2_b, h2buf);
  // h3 = gelu(h2 @ w1 + b1)  (swap_xy=1)
  gemm_bt<<<dim3(64, 32), 256, 0, stream>>>(h2buf, T_a, b1, nullptr, 0, h3buf, 8192, 4096, 1024, 1, 1, 1);
  // out = h3 @ w2 + b2 + x2  (fp32 out, swizzle; direct epilogue)
  gemm_bt<<<dim3(64, 8), 256, 0, stream>>>(h3buf, T_b, b2, x2buf, 1, out, 8192, 1024, 4096, 0, 0, 1);
}